// Round 14
// baseline (1294.561 us; speedup 1.0000x reference)
//
#include <hip/hip_runtime.h>

typedef __attribute__((ext_vector_type(4))) float f32x4;
typedef __attribute__((ext_vector_type(8))) short bf16x8;

#define B_   128
#define T_   1024
#define NROW 131072      // B*T
#define HB   (NROW*300)  // floats in the [B*T][300] matrix
#define NL2E -1.44269504088896340736f   // -log2(e)

__device__ inline unsigned short f2bf(float f) {
    union { float f; unsigned int u; } v; v.f = f;
    unsigned int r = v.u + 0x7FFFu + ((v.u >> 16) & 1u);
    return (unsigned short)(r >> 16);
}

__device__ inline uint4 load8_cvt_s(const float* src, bool rowok, int krem, float scale) {
    f32x4 v0 = {0.f,0.f,0.f,0.f}, v1 = {0.f,0.f,0.f,0.f};
    if (rowok) {
        if (krem >= 8)      { v0 = *(const f32x4*)src; v1 = *(const f32x4*)(src + 4); }
        else if (krem >= 4) { v0 = *(const f32x4*)src; }
    }
    v0 *= scale; v1 *= scale;
    uint4 p;
    p.x = (unsigned)f2bf(v0[0]) | ((unsigned)f2bf(v0[1]) << 16);
    p.y = (unsigned)f2bf(v0[2]) | ((unsigned)f2bf(v0[3]) << 16);
    p.z = (unsigned)f2bf(v1[0]) | ((unsigned)f2bf(v1[1]) << 16);
    p.w = (unsigned)f2bf(v1[2]) | ((unsigned)f2bf(v1[3]) << 16);
    return p;
}

__device__ inline uint4 load8_cvt(const float* src, bool rowok, int krem) {
    return load8_cvt_s(src, rowok, krem, 1.0f);
}

// ---------------------------------------------------------------------------
// K1-T2 (ws path): A'_T4[t][rg=n/4][b][4 bf16] time-major into d_ws; 2 t/block.
// ---------------------------------------------------------------------------
__global__ __launch_bounds__(512) void gemm_in_t2(
    const float* __restrict__ X, const float* __restrict__ W1,
    const float* __restrict__ b1, char* __restrict__ aws)
{
    __shared__ unsigned short wlds[19 * 64 * 8];
    __shared__ unsigned short xlds[2][8 * 64 * 8];
    const int tid = threadIdx.x;
    const int w = tid >> 6, l = tid & 63, lg = l >> 4, ln = l & 15;
    const int th = w >> 2, wb = w & 3;
    const int t = blockIdx.x * 2 + th;

    f32x4 acc[2][19];
    #pragma unroll
    for (int q = 0; q < 2; ++q)
        #pragma unroll
        for (int mt = 0; mt < 19; ++mt) acc[q][mt] = (f32x4){0.f,0.f,0.f,0.f};

    for (int kt = 0; kt < 10; ++kt) {
        const int kc = kt * 32;
        __syncthreads();
        #pragma unroll
        for (int rep = 0; rep < 3; ++rep) {
            int e = tid + rep * 512;
            if (e < 1216) {
                int nn = e >> 2, kh = e & 3;
                int k0 = kc + kh * 8;
                uint4 p = load8_cvt_s(W1 + (size_t)nn * 600 + k0, nn < 300, 300 - k0, NL2E);
                *(uint4*)&wlds[(((nn >> 4) * 64) + kh * 16 + (nn & 15)) * 8] = p;
            }
        }
        #pragma unroll
        for (int tt = 0; tt < 2; ++tt) {
            int e = tid;
            int row = e >> 2, kh = e & 3;
            int k0 = kc + kh * 8;
            uint4 p = load8_cvt(X + ((size_t)row * 1024 + blockIdx.x * 2 + tt) * 300 + k0,
                                true, 300 - k0);
            *(uint4*)&xlds[tt][(((row >> 4) * 64) + kh * 16 + (row & 15)) * 8] = p;
        }
        __syncthreads();
        bf16x8 wfr[19];
        #pragma unroll
        for (int mt = 0; mt < 19; ++mt) wfr[mt] = *(const bf16x8*)&wlds[(mt * 64 + l) * 8];
        #pragma unroll
        for (int q = 0; q < 2; ++q) {
            bf16x8 xfr = *(const bf16x8*)&xlds[th][((wb * 2 + q) * 64 + l) * 8];
            #pragma unroll
            for (int mt = 0; mt < 19; ++mt)
                acc[q][mt] = __builtin_amdgcn_mfma_f32_16x16x32_bf16(wfr[mt], xfr, acc[q][mt], 0, 0, 0);
        }
    }

    char* tb = aws + (size_t)t * 76800;
    #pragma unroll
    for (int q = 0; q < 2; ++q) {
        int b = (wb * 2 + q) * 16 + ln;
        #pragma unroll
        for (int mt = 0; mt < 19; ++mt) {
            int rg = mt * 4 + lg;
            if (rg < 75) {
                f32x4 bias = *(const f32x4*)(b1 + mt * 16 + lg * 4);
                float v0 = acc[q][mt][0] + bias[0] * NL2E;
                float v1 = acc[q][mt][1] + bias[1] * NL2E;
                float v2 = acc[q][mt][2] + bias[2] * NL2E;
                float v3 = acc[q][mt][3] + bias[3] * NL2E;
                unsigned plo, phi;
                asm("v_cvt_pk_bf16_f32 %0, %1, %2" : "=v"(plo) : "v"(v0), "v"(v1));
                asm("v_cvt_pk_bf16_f32 %0, %1, %2" : "=v"(phi) : "v"(v2), "v"(v3));
                uint2 pk; pk.x = plo; pk.y = phi;
                *(uint2*)(tb + (size_t)rg * 1024 + b * 8) = pk;
            }
        }
    }
}

// ---------------------------------------------------------------------------
// K2-SPLIT: recurrence with split publication. 8 blocks x 512 thr.
// Lower waves 0-3 own M-tiles 0-9 (rows 0-159 = kt 0-4 of the K dim);
// upper waves 4-7 own tiles 10-19. Per step: MFMA-lo -> barrier2 (publishes
// h(t-1).hi, written by upper waves at step start) -> MFMA-hi -> lower
// sigmoid+publish h(t).lo -> barrier1. Upper sigmoid of h(t).hi is DEFERRED
// past barrier1 into step t+1's MFMA-lo window (hidden under lower MFMA on
// the same SIMD). h(t) overwrites A'(t) in ws (all A'(t) reads done at t-2).
// ---------------------------------------------------------------------------
#define QK2(q) ((q) < 2 || lo3)

#define SIG4(zin)                                                               \
        f32x4 hv; uint2 pk;                                                     \
        _Pragma("unroll")                                                       \
        for (int i = 0; i < 4; ++i) {                                           \
            float ex, sg;                                                       \
            asm("v_exp_f32 %0, %1" : "=v"(ex) : "v"(zin[i]));                   \
            asm("v_rcp_f32 %0, %1" : "=v"(sg) : "v"(1.0f + ex));                \
            hv[i] = sg;                                                         \
        }                                                                       \
        asm("v_cvt_pk_bf16_f32 %0, %1, %2" : "=v"(pk.x) : "v"(hv[0]), "v"(hv[1])); \
        asm("v_cvt_pk_bf16_f32 %0, %1, %2" : "=v"(pk.y) : "v"(hv[2]), "v"(hv[3]));

#define K2S(RB, tval, AS, FIRST)                                                \
    {                                                                           \
        const int t = (tval);                                                   \
        /* upper: deferred sigmoid + publish h(t-1).hi into hlds[RB].hi */      \
        if (g_up && !(FIRST)) {                                                 \
            _Pragma("unroll")                                                   \
            for (int q = 0; q < 3; ++q) {                                       \
                if (!QK2(q)) continue;                                          \
                SIG4(uacc[q])                                                   \
                *(uint2*)((char*)hlds + (RB) * 10240 + ldsoff[q]) = pk;         \
                if (rq[q] < 300) *(uint2*)(UPT + loff[q]) = pk;                 \
            }                                                                   \
        }                                                                       \
        bf16x8 bfr[5];                                                          \
        _Pragma("unroll")                                                       \
        for (int kt = 0; kt < 5; ++kt)                                          \
            bfr[kt] = *(const bf16x8*)&hlds[RB][(kt * 64 + l) * 8];             \
        f32x4 acc[3], accB[3];                                                  \
        _Pragma("unroll")                                                       \
        for (int q = 0; q < 3; ++q) {                                           \
            union { float f; unsigned u; } u0, u1, u2, u3;                      \
            u0.u = AS[q].x << 16; u1.u = AS[q].x & 0xFFFF0000u;                 \
            u2.u = AS[q].y << 16; u3.u = AS[q].y & 0xFFFF0000u;                 \
            acc[q] = (f32x4){u0.f, u1.f, u2.f, u3.f};                           \
            accB[q] = (f32x4){0.f, 0.f, 0.f, 0.f};                              \
        }                                                                       \
        /* prefetch A'(t+2) */                                                  \
        _Pragma("unroll")                                                       \
        for (int q = 0; q < 3; ++q)                                             \
            if (QK2(q)) AS[q] = *(const uint2*)(LWT + 153600 + loff[q]);        \
        __builtin_amdgcn_s_setprio(1);                                          \
        _Pragma("unroll")                                                       \
        for (int kt = 0; kt < 3; ++kt) {                                        \
            acc[0] = __builtin_amdgcn_mfma_f32_16x16x32_bf16(afrag[0][kt], bfr[kt], acc[0], 0, 0, 0); \
            acc[1] = __builtin_amdgcn_mfma_f32_16x16x32_bf16(afrag[1][kt], bfr[kt], acc[1], 0, 0, 0); \
            if (lo3)                                                            \
                acc[2] = __builtin_amdgcn_mfma_f32_16x16x32_bf16(afrag[2][kt], bfr[kt], acc[2], 0, 0, 0); \
        }                                                                       \
        _Pragma("unroll")                                                       \
        for (int kt = 3; kt < 5; ++kt) {                                        \
            accB[0] = __builtin_amdgcn_mfma_f32_16x16x32_bf16(afrag[0][kt], bfr[kt], accB[0], 0, 0, 0); \
            accB[1] = __builtin_amdgcn_mfma_f32_16x16x32_bf16(afrag[1][kt], bfr[kt], accB[1], 0, 0, 0); \
            if (lo3)                                                            \
                accB[2] = __builtin_amdgcn_mfma_f32_16x16x32_bf16(afrag[2][kt], bfr[kt], accB[2], 0, 0, 0); \
        }                                                                       \
        __builtin_amdgcn_s_setprio(0);                                          \
        asm volatile("s_waitcnt lgkmcnt(0)" ::: "memory");                      \
        __builtin_amdgcn_s_barrier();   /* barrier2: h(t-1).hi visible */       \
        asm volatile("" ::: "memory");                                          \
        _Pragma("unroll")                                                       \
        for (int kt = 0; kt < 5; ++kt)                                          \
            bfr[kt] = *(const bf16x8*)&hlds[RB][((kt + 5) * 64 + l) * 8];       \
        __builtin_amdgcn_s_setprio(1);                                          \
        _Pragma("unroll")                                                       \
        for (int kt = 0; kt < 3; ++kt) {                                        \
            acc[0] = __builtin_amdgcn_mfma_f32_16x16x32_bf16(afrag[0][kt + 5], bfr[kt], acc[0], 0, 0, 0); \
            acc[1] = __builtin_amdgcn_mfma_f32_16x16x32_bf16(afrag[1][kt + 5], bfr[kt], acc[1], 0, 0, 0); \
            if (lo3)                                                            \
                acc[2] = __builtin_amdgcn_mfma_f32_16x16x32_bf16(afrag[2][kt + 5], bfr[kt], acc[2], 0, 0, 0); \
        }                                                                       \
        _Pragma("unroll")                                                       \
        for (int kt = 3; kt < 5; ++kt) {                                        \
            accB[0] = __builtin_amdgcn_mfma_f32_16x16x32_bf16(afrag[0][kt + 5], bfr[kt], accB[0], 0, 0, 0); \
            accB[1] = __builtin_amdgcn_mfma_f32_16x16x32_bf16(afrag[1][kt + 5], bfr[kt], accB[1], 0, 0, 0); \
            if (lo3)                                                            \
                accB[2] = __builtin_amdgcn_mfma_f32_16x16x32_bf16(afrag[2][kt + 5], bfr[kt], accB[2], 0, 0, 0); \
        }                                                                       \
        __builtin_amdgcn_s_setprio(0);                                          \
        if (!g_up) {                                                            \
            _Pragma("unroll")                                                   \
            for (int q = 0; q < 3; ++q) {                                       \
                if (!QK2(q)) continue;                                          \
                f32x4 z;                                                        \
                _Pragma("unroll")                                               \
                for (int i = 0; i < 4; ++i) z[i] = acc[q][i] + accB[q][i];      \
                SIG4(z)                                                         \
                *(uint2*)((char*)hlds + ((RB) ^ 1) * 10240 + ldsoff[q]) = pk;   \
                *(uint2*)(LWT + loff[q]) = pk;    /* lower rows all < 300 */    \
                if (t == T_ - 1)                                                \
                    *(f32x4*)(hfinal + bb * 300 + rq[q]) = hv;                  \
            }                                                                   \
        } else {                                                                \
            _Pragma("unroll")                                                   \
            for (int q = 0; q < 3; ++q) {                                       \
                if (!QK2(q)) continue;                                          \
                _Pragma("unroll")                                               \
                for (int i = 0; i < 4; ++i) uacc[q][i] = acc[q][i] + accB[q][i]; \
            }                                                                   \
        }                                                                       \
        LWT += 76800; UPT += 76800;                                             \
        asm volatile("s_waitcnt lgkmcnt(0)" ::: "memory");                      \
        __builtin_amdgcn_s_barrier();   /* barrier1: h(t).lo visible */         \
        asm volatile("" ::: "memory");                                          \
    }

__global__ __launch_bounds__(512) void elman_rec_ws(
    const float* __restrict__ W1, float* __restrict__ hfinal,
    char* __restrict__ hws)
{
    __shared__ unsigned short hlds[2][10 * 64 * 8];   // 2 x 10240 B
    const int tid = threadIdx.x;
    const int w = tid >> 6, l = tid & 63, lg = l >> 4, ln = l & 15;
    const int g_up = w >> 2;              // 0 = lower (tiles 0-9), 1 = upper
    const int wl = w & 3;
    const bool lo3 = (wl < 2);            // waves 0,1 (4,5) carry 3 tiles
    const int tbase = g_up * 10 + (lo3 ? wl * 3 : 6 + (wl - 2) * 2);
    const int bb = blockIdx.x * 16 + ln;

    int rq[3], ldsoff[3], loff[3];
    #pragma unroll
    for (int q = 0; q < 3; ++q) {
        int r = (tbase + q) * 16 + 4 * lg;
        rq[q] = r;
        ldsoff[q] = (((r >> 5) * 64 + ((r >> 3) & 3) * 16 + ln) * 8 + (r & 7)) * 2;
        int rgc = r >> 2; if (rgc > 74) rgc = 74;
        loff[q] = rgc * 1024 + bb * 8;
    }

    // W1h A-fragments, -log2e-scaled (rows >=300, k>=300 zeroed)
    bf16x8 afrag[3][10];
    #pragma unroll
    for (int q = 0; q < 3; ++q) {
        #pragma unroll
        for (int kt = 0; kt < 10; ++kt) {
            bool qa = QK2(q);
            int r = (tbase + q) * 16 + ln;
            int k0 = kt * 32 + lg * 8;
            uint4 p = load8_cvt_s(W1 + (size_t)r * 600 + 300 + k0,
                                  qa && r < 300, 300 - k0, NL2E);
            union { uint4 u; bf16x8 s; } cv; cv.u = p;
            afrag[q][kt] = cv.s;
        }
    }

    for (int i = tid; i < 10 * 64 * 8; i += 512) hlds[0][i] = 0;   // h(-1) = 0

    char* LWT = hws;              // h(t)/A'(t) slot, advanced per step
    char* UPT = hws - 76800;      // h(t-1) slot for deferred upper stores

    uint2 AS0[3], AS1[3];
    f32x4 uacc[3];
    #pragma unroll
    for (int q = 0; q < 3; ++q) {
        uacc[q] = (f32x4){0.f,0.f,0.f,0.f};
        if (QK2(q)) {
            AS0[q] = *(const uint2*)(hws + loff[q]);            // A'(0)
            AS1[q] = *(const uint2*)(hws + 76800 + loff[q]);    // A'(1)
        }
    }
    __syncthreads();

    K2S(0, 0, AS0, true)                      // t = 0
    for (int t2 = 1; t2 < 1023; t2 += 2) {
        K2S(1, t2,     AS1, false)
        K2S(0, t2 + 1, AS0, false)
    }
    K2S(1, 1023, AS1, false)                  // t = 1023

    // epilogue: upper h(1023).hi global store + hfinal
    if (g_up) {
        #pragma unroll
        for (int q = 0; q < 3; ++q) {
            if (!QK2(q)) continue;
            SIG4(uacc[q])
            if (rq[q] < 300) {
                *(uint2*)(UPT + loff[q]) = pk;
                *(f32x4*)(hfinal + bb * 300 + rq[q]) = hv;
            }
        }
    }
}

// ---------------------------------------------------------------------------
// K3-T2: out[b][t][n] = sum_r h_T4[t][r][b]*W2[n][r] + b2[n]; 2 t/block.
// ---------------------------------------------------------------------------
__global__ __launch_bounds__(512) void gemm_out_t2(
    const char* __restrict__ hws, const float* __restrict__ W2,
    const float* __restrict__ b2, float* __restrict__ out)
{
    __shared__ unsigned short ahs[2][8 * 132 * 4];
    __shared__ unsigned short blds[19 * 64 * 8];
    const int tid = threadIdx.x;
    const int w = tid >> 6, l = tid & 63, lg = l >> 4, ln = l & 15;
    const int th = w >> 2, wb = w & 3;
    const int t = blockIdx.x * 2 + th;

    f32x4 acc[2][19];
    #pragma unroll
    for (int q = 0; q < 2; ++q)
        #pragma unroll
        for (int nt = 0; nt < 19; ++nt) acc[q][nt] = (f32x4){0.f,0.f,0.f,0.f};

    for (int kt = 0; kt < 10; ++kt) {
        const int kc = kt * 32;
        __syncthreads();
        #pragma unroll
        for (int tt = 0; tt < 2; ++tt) {
            const char* hbase = hws + (size_t)(blockIdx.x * 2 + tt) * 76800;
            #pragma unroll
            for (int it = 0; it < 2; ++it) {
                int e = tid + it * 512;
                int rg = e >> 7, b = e & 127;
                int rgg = kt * 8 + rg;
                uint2 v = make_uint2(0u, 0u);
                if (rgg < 75) v = *(const uint2*)(hbase + (size_t)rgg * 1024 + b * 8);
                *(uint2*)&ahs[tt][(rg * 132 + b) * 4] = v;
            }
        }
        #pragma unroll
        for (int rep = 0; rep < 3; ++rep) {
            int e = tid + rep * 512;
            if (e < 1216) {
                int nn = e >> 2, kh = e & 3;
                int k0 = kc + kh * 8;
                uint4 p = load8_cvt(W2 + (size_t)nn * 300 + k0, nn < 300, 300 - k0);
                *(uint4*)&blds[(((nn >> 4) * 64) + kh * 16 + (nn & 15)) * 8] = p;
            }
        }
        __syncthreads();
        bf16x8 bfr[19];
        #pragma unroll
        for (int nt = 0; nt < 19; ++nt) bfr[nt] = *(const bf16x8*)&blds[(nt * 64 + l) * 8];
        #pragma unroll
        for (int q = 0; q < 2; ++q) {
            int b = (wb * 2 + q) * 16 + ln;
            uint2 u0 = *(const uint2*)&ahs[th][((2 * lg)     * 132 + b) * 4];
            uint2 u1 = *(const uint2*)&ahs[th][((2 * lg + 1) * 132 + b) * 4];
            union { uint4 u; bf16x8 s; } cv;
            cv.u.x = u0.x; cv.u.y = u0.y; cv.u.z = u1.x; cv.u.w = u1.y;
            bf16x8 afr = cv.s;
            #pragma unroll
            for (int nt = 0; nt < 19; ++nt)
                acc[q][nt] = __builtin_amdgcn_mfma_f32_16x16x32_bf16(afr, bfr[nt], acc[q][nt], 0, 0, 0);
        }
    }

    #pragma unroll
    for (int q = 0; q < 2; ++q)
        #pragma unroll
        for (int nt = 0; nt < 19; ++nt) {
            int n = nt * 16 + ln;
            if (n < 300) {
                float bias = b2[n];
                int b0r = (wb * 2 + q) * 16 + lg * 4;
                #pragma unroll
                for (int i = 0; i < 4; ++i)
                    out[((size_t)(b0r + i) * T_ + t) * 300 + n] = acc[q][nt][i] + bias;
            }
        }
}

// ---------------------------------------------------------------------------
// FALLBACK path (small ws): R9 kernels, unchanged.
// ---------------------------------------------------------------------------
#define QOK(q) ((q) < 2 || w4)

__global__ __launch_bounds__(256) void gemm_in(
    const float* __restrict__ X, const float* __restrict__ W1,
    const float* __restrict__ b1, float* __restrict__ A)
{
    __shared__ unsigned short alds[8 * 64 * 8];
    __shared__ unsigned short blds[10 * 64 * 8];
    const int tid = threadIdx.x;
    const int w = tid >> 6, l = tid & 63, lg = l >> 4, ln = l & 15;
    const size_t m0 = (size_t)blockIdx.x * 128;
    const int n0 = blockIdx.y * 160;

    f32x4 acc[2][10];
    #pragma unroll
    for (int q = 0; q < 2; ++q)
        #pragma unroll
        for (int nt = 0; nt < 10; ++nt) acc[q][nt] = (f32x4){0.f,0.f,0.f,0.f};

    for (int kt = 0; kt < 10; ++kt) {
        const int kc = kt * 32;
        __syncthreads();
        #pragma unroll
        for (int rep = 0; rep < 2; ++rep) {
            int e = tid + rep * 256;
            int row = e >> 2, kh = e & 3;
            int k0 = kc + kh * 8;
            uint4 p = load8_cvt(X + (m0 + row) * 300 + k0, true, 300 - k0);
            *(uint4*)&alds[(((row >> 4) * 64) + kh * 16 + (row & 15)) * 8] = p;
        }
        #pragma unroll
        for (int rep = 0; rep < 3; ++rep) {
            int e = tid + rep * 256;
            if (e < 640) {
                int nn = e >> 2, kh = e & 3;
                int n = n0 + nn;
                int k0 = kc + kh * 8;
                uint4 p = load8_cvt(W1 + (size_t)n * 600 + k0, n < 300, 300 - k0);
                *(uint4*)&blds[(((nn >> 4) * 64) + kh * 16 + (nn & 15)) * 8] = p;
            }
        }
        __syncthreads();
        bf16x8 bfr[10];
        #pragma unroll
        for (int nt = 0; nt < 10; ++nt) bfr[nt] = *(const bf16x8*)&blds[(nt * 64 + l) * 8];
        #pragma unroll
        for (int q = 0; q < 2; ++q) {
            bf16x8 afr = *(const bf16x8*)&alds[((w * 2 + q) * 64 + l) * 8];
            #pragma unroll
            for (int nt = 0; nt < 10; ++nt)
                acc[q][nt] = __builtin_amdgcn_mfma_f32_16x16x32_bf16(afr, bfr[nt], acc[q][nt], 0, 0, 0);
        }
    }

    #pragma unroll
    for (int q = 0; q < 2; ++q)
        #pragma unroll
        for (int nt = 0; nt < 10; ++nt) {
            int n = n0 + nt * 16 + ln;
            if (n < 300) {
                float bias = b1[n];
                size_t mr = m0 + (w * 2 + q) * 16 + lg * 4;
                #pragma unroll
                for (int i = 0; i < 4; ++i)
                    A[(mr + i) * 300 + n] = (acc[q][nt][i] + bias) * NL2E;
            }
        }
}

#define K2_STEP(P, tval, ASLOT, APTR, HPME, HPOTHER)                            \
    {                                                                           \
        const int t = (tval);                                                   \
        const int tt = t - 1;                                                   \
        const size_t so = (size_t)(tt >> 6) * 76800 + (size_t)(tt & 63) * 600;  \
        bf16x8 bfr[10];                                                         \
        _Pragma("unroll")                                                       \
        for (int kt = 0; kt < 10; ++kt)                                         \
            bfr[kt] = *(const bf16x8*)&hlds[P][(kt * 64 + l) * 8];              \
        f32x4 acc[3], accB[3];                                                  \
        _Pragma("unroll")                                                       \
        for (int q = 0; q < 3; ++q) {                                           \
            acc[q] = QOK(q) ? ASLOT[q] : (f32x4){0.f,0.f,0.f,0.f};              \
            accB[q] = (f32x4){0.f,0.f,0.f,0.f};                                 \
        }                                                                       \
        _Pragma("unroll")                                                       \
        for (int q = 0; q < 3; ++q)                                             \
            if (QOK(q)) ASLOT[q] = *(const f32x4*)(APTR + rq[q] * 4);           \
        APTR += 2400;                                                           \
        __builtin_amdgcn_s_setprio(1);                                          \
        _Pragma("unroll")                                                       \
        for (int kt = 0; kt < 5; ++kt) {                                        \
            acc[0]  = __builtin_amdgcn_mfma_f32_16x16x32_bf16(afrag[0][kt],   bfr[kt],   acc[0],  0, 0, 0); \
            accB[0] = __builtin_amdgcn_mfma_f32_16x16x32_bf16(afrag[0][kt+5], bfr[kt+5], accB[0], 0, 0, 0); \
            acc[1]  = __builtin_amdgcn_mfma_f32_16x16x32_bf16(afrag[1][kt],   bfr[kt],   acc[1],  0, 0, 0); \
            accB[1] = __builtin_amdgcn_mfma_f32_16x16x32_bf16(afrag[1][kt+5], bfr[kt+5], accB[1], 0, 0, 0); \
            if (w4) {                                                           \
                acc[2]  = __builtin_amdgcn_mfma_f32_16x16x32_bf16(afrag[2][kt],   bfr[kt],   acc[2],  0, 0, 0); \
                accB[2] = __builtin_amdgcn_mfma_f32_16x16x32_bf16(afrag[2][kt+5], bfr[kt+5], accB[2], 0, 0, 0); \
            }                                                                   \
        }                                                                       \
        __builtin_amdgcn_s_setprio(0);                                          \
        _Pragma("unroll")                                                       \
        for (int q = 0; q < 3; ++q) {                                           \
            if (!QOK(q)) continue;                                              \
            f32x4 hv;                                                           \
            _Pragma("unroll")                                                   \
            for (int i = 0; i < 4; ++i) {                                       \
                float zn = acc[q][i] + accB[q][i];                              \
                float ex, sg;                                                   \
                asm("v_exp_f32 %0, %1" : "=v"(ex) : "v"(zn));                   \
                asm("v_rcp_f32 %0, %1" : "=v"(sg) : "v"(1.0f + ex));            \
                hv[i] = sg;                                                     \
            }                                                                   \
            unsigned plo, phi;                                                  \
            asm("v_cvt_pk_bf16_f32 %0, %1, %2" : "=v"(plo) : "v"(hv[0]), "v"(hv[1])); \
            asm("v_cvt_pk_bf16_f32 %0, %1, %2" : "=v"(phi) : "v"(hv[2]), "v"(hv[3])); \
            HPME[q].x = plo; HPME[q].y = phi;                                   \
            *(uint2*)((char*)hlds + ((P) ^ 1) * 10240 + ldsoff[q]) = HPME[q];   \
            if (t > 0 && rq[q] < 300)                                           \
                *(uint2*)(sbase + so + rq[q] * 2) = HPOTHER[q];                 \
        }                                                                       \
        asm volatile("s_waitcnt lgkmcnt(0)" ::: "memory");                      \
        __builtin_amdgcn_s_barrier();                                           \
        asm volatile("" ::: "memory");                                          \
    }

__global__ __launch_bounds__(512) void elman_rec_mfma(
    const float* __restrict__ W1, float* __restrict__ buf,
    float* __restrict__ hfinal)
{
    __shared__ unsigned short hlds[2][10 * 64 * 8];
    const int tid = threadIdx.x;
    const int w = tid >> 6, l = tid & 63, lg = l >> 4, ln = l & 15;
    const bool w4 = (w < 4);
    const int bb = blockIdx.x * 16 + ln;

    int rq[3], ldsoff[3];
    #pragma unroll
    for (int q = 0; q < 3; ++q) {
        int tile = w4 ? (3 * w + q) : (12 + 2 * (w - 4) + q);
        int r = tile * 16 + 4 * lg;
        rq[q] = r;
        ldsoff[q] = (((r >> 5) * 64 + ((r >> 3) & 3) * 16 + ln) * 8 + (r & 7)) * 2;
    }

    bf16x8 afrag[3][10];
    #pragma unroll
    for (int q = 0; q < 3; ++q) {
        #pragma unroll
        for (int kt = 0; kt < 10; ++kt) {
            bool qa = (q < 2) || w4;
            int tile = w4 ? (3 * w + q) : (12 + 2 * (w - 4) + q);
            int r = tile * 16 + ln;
            int k0 = kt * 32 + lg * 8;
            uint4 p = load8_cvt_s(W1 + (size_t)r * 600 + 300 + k0,
                                  qa && r < 300, 300 - k0, NL2E);
            union { uint4 u; bf16x8 s; } cv; cv.u = p;
            afrag[q][kt] = cv.s;
        }
    }

    for (int i = tid; i < 10 * 64 * 8; i += 512) hlds[0][i] = 0;

    const char* abase = (const char*)(buf + (size_t)bb * T_ * 300);
    char* sbase = (char*)buf + (size_t)bb * 16 * 76800;

    f32x4 A0[3], A1[3];
    #pragma unroll
    for (int q = 0; q < 3; ++q)
        if (QOK(q)) {
            A0[q] = *(const f32x4*)(abase + rq[q] * 4);
            A1[q] = *(const f32x4*)(abase + 1200 + rq[q] * 4);
        }
    const char* aptr0 = abase + 2400;
    const char* aptr1 = abase + 3600;
    uint2 hpA[3], hpB[3];
    __syncthreads();

    for (int t2 = 0; t2 < T_; t2 += 2) {
        K2_STEP(0, t2,     A0, aptr0, hpA, hpB)
        K2_STEP(1, t2 + 1, A1, aptr1, hpB, hpA)
    }

    {
        const int tt = T_ - 1;
        const size_t so = (size_t)(tt >> 6) * 76800 + (size_t)(tt & 63) * 600;
        #pragma unroll
        for (int q = 0; q < 3; ++q)
            if (QOK(q) && rq[q] < 300) {
                *(uint2*)(sbase + so + rq[q] * 2) = hpB[q];
                f32x4 hv;
                union { float f; unsigned u; } c0, c1, c2, c3;
                c0.u = hpB[q].x << 16; c1.u = hpB[q].x & 0xFFFF0000u;
                c2.u = hpB[q].y << 16; c3.u = hpB[q].y & 0xFFFF0000u;
                hv[0] = c0.f; hv[1] = c1.f; hv[2] = c2.f; hv[3] = c3.f;
                *(f32x4*)(hfinal + bb * 300 + rq[q]) = hv;
            }
    }
}

__global__ __launch_bounds__(256) void gemm_out(
    float* __restrict__ buf, const float* __restrict__ W2,
    const float* __restrict__ b2)
{
    __shared__ unsigned short alds[4 * 64 * 8];
    __shared__ unsigned short blds[19 * 64 * 8];
    const int tid = threadIdx.x;
    const int w = tid >> 6, l = tid & 63, lg = l >> 4, ln = l & 15;
    const size_t chunk = blockIdx.x;
    const char* pbase = (const char*)buf + chunk * 76800;

    f32x4 acc[19];
    #pragma unroll
    for (int nt = 0; nt < 19; ++nt) acc[nt] = (f32x4){0.f,0.f,0.f,0.f};

    for (int kt = 0; kt < 10; ++kt) {
        const int kc = kt * 32;
        __syncthreads();
        {
            int row = tid >> 2, kh = tid & 3;
            int k0 = kc + kh * 8;
            const char* p = pbase + row * 600;
            uint2 lo = make_uint2(0u, 0u), hi = make_uint2(0u, 0u);
            int krem = 300 - k0;
            if (krem >= 8)      { lo = *(const uint2*)(p + k0 * 2); hi = *(const uint2*)(p + k0 * 2 + 8); }
            else if (krem >= 4) { lo = *(const uint2*)(p + k0 * 2); }
            uint4 pk; pk.x = lo.x; pk.y = lo.y; pk.z = hi.x; pk.w = hi.y;
            *(uint4*)&alds[(((row >> 4) * 64) + kh * 16 + (row & 15)) * 8] = pk;
        }
        #pragma unroll
        for (int rep = 0; rep < 5; ++rep) {
            int e = tid + rep * 256;
            if (e < 1216) {
                int nn = e >> 2, kh = e & 3;
                int k0 = kc + kh * 8;
                uint4 p = load8_cvt(W2 + (size_t)nn * 300 + k0, nn < 300, 300 - k0);
                *(uint4*)&blds[(((nn >> 4) * 64) + kh * 16 + (nn & 15)) * 8] = p;
            }
        }
        __syncthreads();
        bf16x8 afr = *(const bf16x8*)&alds[(w * 64 + l) * 8];
        #pragma unroll
        for (int nt = 0; nt < 19; ++nt) {
            bf16x8 bfr = *(const bf16x8*)&blds[(nt * 64 + l) * 8];
            acc[nt] = __builtin_amdgcn_mfma_f32_16x16x32_bf16(afr, bfr, acc[nt], 0, 0, 0);
        }
    }

    float* frow = buf + chunk * 19200;
    #pragma unroll
    for (int nt = 0; nt < 19; ++nt) {
        int n = nt * 16 + ln;
        if (n < 300) {
            float bias = b2[n];
            int mr = w * 16 + lg * 4;
            #pragma unroll
            for (int i = 0; i < 4; ++i)
                frow[(mr + i) * 300 + n] = acc[nt][i] + bias;
        }
    }
}

// ---------------------------------------------------------------------------
extern "C" void kernel_launch(void* const* d_in, const int* in_sizes, int n_in,
                              void* d_out, int out_size, void* d_ws, size_t ws_size,
                              hipStream_t stream)
{
    const float* x  = (const float*)d_in[0];
    const float* W1 = (const float*)d_in[1];
    const float* b1 = (const float*)d_in[2];
    const float* W2 = (const float*)d_in[3];
    const float* b2 = (const float*)d_in[4];

    float* out    = (float*)d_out;
    float* hfinal = out + (size_t)HB;

    const size_t HT4 = (size_t)T_ * 75 * 128 * 8;   // 78,643,200 B
    if (ws_size >= HT4 + 2 * 76800) {               // + prefetch overrun slack
        gemm_in_t2<<<512, 512, 0, stream>>>(x, W1, b1, (char*)d_ws);
        elman_rec_ws<<<8, 512, 0, stream>>>(W1, hfinal, (char*)d_ws);
        gemm_out_t2<<<512, 512, 0, stream>>>((const char*)d_ws, W2, b2, out);
    } else {
        gemm_in<<<dim3(1024, 2), 256, 0, stream>>>(x, W1, b1, out);
        elman_rec_mfma<<<8, 512, 0, stream>>>(W1, out, hfinal);
        gemm_out<<<2048, 256, 0, stream>>>(out, W2, b2);
    }
}

// Round 15
// 991.285 us; speedup vs baseline: 1.3059x; 1.3059x over previous
//
#include <hip/hip_runtime.h>

typedef __attribute__((ext_vector_type(4))) float f32x4;
typedef __attribute__((ext_vector_type(8))) short bf16x8;

#define B_   128
#define T_   1024
#define NROW 131072      // B*T
#define HB   (NROW*300)  // floats in the [B*T][300] matrix
#define NL2E -1.44269504088896340736f   // -log2(e)

__device__ inline unsigned short f2bf(float f) {
    union { float f; unsigned int u; } v; v.f = f;
    unsigned int r = v.u + 0x7FFFu + ((v.u >> 16) & 1u);
    return (unsigned short)(r >> 16);
}

__device__ inline uint4 load8_cvt_s(const float* src, bool rowok, int krem, float scale) {
    f32x4 v0 = {0.f,0.f,0.f,0.f}, v1 = {0.f,0.f,0.f,0.f};
    if (rowok) {
        if (krem >= 8)      { v0 = *(const f32x4*)src; v1 = *(const f32x4*)(src + 4); }
        else if (krem >= 4) { v0 = *(const f32x4*)src; }
    }
    v0 *= scale; v1 *= scale;
    uint4 p;
    p.x = (unsigned)f2bf(v0[0]) | ((unsigned)f2bf(v0[1]) << 16);
    p.y = (unsigned)f2bf(v0[2]) | ((unsigned)f2bf(v0[3]) << 16);
    p.z = (unsigned)f2bf(v1[0]) | ((unsigned)f2bf(v1[1]) << 16);
    p.w = (unsigned)f2bf(v1[2]) | ((unsigned)f2bf(v1[3]) << 16);
    return p;
}

__device__ inline uint4 load8_cvt(const float* src, bool rowok, int krem) {
    return load8_cvt_s(src, rowok, krem, 1.0f);
}

// ---------------------------------------------------------------------------
// K1-T2 (ws path): A'_T4[t][rg=n/4][b][4 bf16] time-major into d_ws; 2 t/block.
// ---------------------------------------------------------------------------
__global__ __launch_bounds__(512) void gemm_in_t2(
    const float* __restrict__ X, const float* __restrict__ W1,
    const float* __restrict__ b1, char* __restrict__ aws)
{
    __shared__ unsigned short wlds[19 * 64 * 8];
    __shared__ unsigned short xlds[2][8 * 64 * 8];
    const int tid = threadIdx.x;
    const int w = tid >> 6, l = tid & 63, lg = l >> 4, ln = l & 15;
    const int th = w >> 2, wb = w & 3;
    const int t = blockIdx.x * 2 + th;

    f32x4 acc[2][19];
    #pragma unroll
    for (int q = 0; q < 2; ++q)
        #pragma unroll
        for (int mt = 0; mt < 19; ++mt) acc[q][mt] = (f32x4){0.f,0.f,0.f,0.f};

    for (int kt = 0; kt < 10; ++kt) {
        const int kc = kt * 32;
        __syncthreads();
        #pragma unroll
        for (int rep = 0; rep < 3; ++rep) {
            int e = tid + rep * 512;
            if (e < 1216) {
                int nn = e >> 2, kh = e & 3;
                int k0 = kc + kh * 8;
                uint4 p = load8_cvt_s(W1 + (size_t)nn * 600 + k0, nn < 300, 300 - k0, NL2E);
                *(uint4*)&wlds[(((nn >> 4) * 64) + kh * 16 + (nn & 15)) * 8] = p;
            }
        }
        #pragma unroll
        for (int tt = 0; tt < 2; ++tt) {
            int e = tid;
            int row = e >> 2, kh = e & 3;
            int k0 = kc + kh * 8;
            uint4 p = load8_cvt(X + ((size_t)row * 1024 + blockIdx.x * 2 + tt) * 300 + k0,
                                true, 300 - k0);
            *(uint4*)&xlds[tt][(((row >> 4) * 64) + kh * 16 + (row & 15)) * 8] = p;
        }
        __syncthreads();
        bf16x8 wfr[19];
        #pragma unroll
        for (int mt = 0; mt < 19; ++mt) wfr[mt] = *(const bf16x8*)&wlds[(mt * 64 + l) * 8];
        #pragma unroll
        for (int q = 0; q < 2; ++q) {
            bf16x8 xfr = *(const bf16x8*)&xlds[th][((wb * 2 + q) * 64 + l) * 8];
            #pragma unroll
            for (int mt = 0; mt < 19; ++mt)
                acc[q][mt] = __builtin_amdgcn_mfma_f32_16x16x32_bf16(wfr[mt], xfr, acc[q][mt], 0, 0, 0);
        }
    }

    char* tb = aws + (size_t)t * 76800;
    #pragma unroll
    for (int q = 0; q < 2; ++q) {
        int b = (wb * 2 + q) * 16 + ln;
        #pragma unroll
        for (int mt = 0; mt < 19; ++mt) {
            int rg = mt * 4 + lg;
            if (rg < 75) {
                f32x4 bias = *(const f32x4*)(b1 + mt * 16 + lg * 4);
                float v0 = acc[q][mt][0] + bias[0] * NL2E;
                float v1 = acc[q][mt][1] + bias[1] * NL2E;
                float v2 = acc[q][mt][2] + bias[2] * NL2E;
                float v3 = acc[q][mt][3] + bias[3] * NL2E;
                unsigned plo, phi;
                asm("v_cvt_pk_bf16_f32 %0, %1, %2" : "=v"(plo) : "v"(v0), "v"(v1));
                asm("v_cvt_pk_bf16_f32 %0, %1, %2" : "=v"(phi) : "v"(v2), "v"(v3));
                uint2 pk; pk.x = plo; pk.y = phi;
                *(uint2*)(tb + (size_t)rg * 1024 + b * 8) = pk;
            }
        }
    }
}

#define QOK(q) ((q) < 2 || w4)

// ---------------------------------------------------------------------------
// K2-WS3 (R12/R13 best): recurrence; A'/h in d_ws time-major (h(t) overwrites
// A'(t) in place; race-free). 8 blocks x 512 thr. Per-q MFMA/sigmoid
// interleave; uniform time pointer + constant lane offsets; exp2 sigmoid;
// one lgkmcnt(0)+s_barrier per step.
// ---------------------------------------------------------------------------
#define K2_CHAIN(q)                                                             \
    _Pragma("unroll")                                                           \
    for (int kt = 0; kt < 5; ++kt) {                                            \
        acc[q]  = __builtin_amdgcn_mfma_f32_16x16x32_bf16(afrag[q][kt],   bfr[kt],   acc[q],  0, 0, 0); \
        accB[q] = __builtin_amdgcn_mfma_f32_16x16x32_bf16(afrag[q][kt+5], bfr[kt+5], accB[q], 0, 0, 0); \
    }

#define K2_SIG(q, P, HWT, t)                                                    \
    {                                                                           \
        f32x4 hv;                                                               \
        _Pragma("unroll")                                                       \
        for (int i = 0; i < 4; ++i) {                                           \
            float zn = acc[q][i] + accB[q][i];      /* = -z*log2e */            \
            float ex, sg;                                                       \
            asm("v_exp_f32 %0, %1" : "=v"(ex) : "v"(zn));                       \
            asm("v_rcp_f32 %0, %1" : "=v"(sg) : "v"(1.0f + ex));                \
            hv[i] = sg;                                                         \
        }                                                                       \
        unsigned plo, phi;                                                      \
        asm("v_cvt_pk_bf16_f32 %0, %1, %2" : "=v"(plo) : "v"(hv[0]), "v"(hv[1])); \
        asm("v_cvt_pk_bf16_f32 %0, %1, %2" : "=v"(phi) : "v"(hv[2]), "v"(hv[3])); \
        uint2 pk; pk.x = plo; pk.y = phi;                                       \
        *(uint2*)((char*)hlds + ((P) ^ 1) * 10240 + ldsoff[q]) = pk;            \
        if (rq[q] < 300) {                                                      \
            *(uint2*)((HWT) + loff[q]) = pk;    /* h(t) overwrites A'(t) */     \
            if ((t) == T_ - 1)                                                  \
                *(f32x4*)(hfinal + bb * 300 + rq[q]) = hv;                      \
        }                                                                       \
    }

#define K2W_STEP(P, tval, AS, HWT)                                              \
    {                                                                           \
        const int t = (tval);                                                   \
        bf16x8 bfr[10];                                                         \
        _Pragma("unroll")                                                       \
        for (int kt = 0; kt < 10; ++kt)                                         \
            bfr[kt] = *(const bf16x8*)&hlds[P][(kt * 64 + l) * 8];              \
        f32x4 acc[3], accB[3];                                                  \
        _Pragma("unroll")                                                       \
        for (int q = 0; q < 3; ++q) {                                           \
            union { float f; unsigned u; } u0, u1, u2, u3;                      \
            u0.u = AS[q].x << 16; u1.u = AS[q].x & 0xFFFF0000u;                 \
            u2.u = AS[q].y << 16; u3.u = AS[q].y & 0xFFFF0000u;                 \
            acc[q] = (f32x4){u0.f, u1.f, u2.f, u3.f};                           \
            accB[q] = (f32x4){0.f,0.f,0.f,0.f};                                 \
        }                                                                       \
        /* prefetch A'(t+2): uniform base + const lane offset */                \
        _Pragma("unroll")                                                       \
        for (int q = 0; q < 3; ++q)                                             \
            if (QOK(q)) AS[q] = *(const uint2*)((HWT) + 153600 + loff[q]);      \
        __builtin_amdgcn_s_setprio(1);                                          \
        K2_CHAIN(0)                                                             \
        K2_CHAIN(1)                                                             \
        __builtin_amdgcn_s_setprio(0);                                          \
        K2_SIG(0, P, HWT, t)                                                    \
        if (w4) {                                                               \
            __builtin_amdgcn_s_setprio(1);                                      \
            K2_CHAIN(2)                                                         \
            __builtin_amdgcn_s_setprio(0);                                      \
        }                                                                       \
        K2_SIG(1, P, HWT, t)                                                    \
        if (w4) K2_SIG(2, P, HWT, t)                                            \
        HWT += 153600;                                                          \
        asm volatile("s_waitcnt lgkmcnt(0)" ::: "memory");                      \
        __builtin_amdgcn_s_barrier();                                           \
        asm volatile("" ::: "memory");                                          \
    }

__global__ __launch_bounds__(512) void elman_rec_ws(
    const float* __restrict__ W1, float* __restrict__ hfinal,
    char* __restrict__ hws)
{
    __shared__ unsigned short hlds[2][10 * 64 * 8];   // 2 x 10240 B
    const int tid = threadIdx.x;
    const int w = tid >> 6, l = tid & 63, lg = l >> 4, ln = l & 15;
    const bool w4 = (w < 4);
    const int bb = blockIdx.x * 16 + ln;    // this lane's batch (B/C column)

    int rq[3], ldsoff[3], loff[3];
    #pragma unroll
    for (int q = 0; q < 3; ++q) {
        int tile = w4 ? (3 * w + q) : (12 + 2 * (w - 4) + q);
        int r = tile * 16 + 4 * lg;
        rq[q] = r;
        ldsoff[q] = (((r >> 5) * 64 + ((r >> 3) & 3) * 16 + ln) * 8 + (r & 7)) * 2;
        int rgc = r >> 2; if (rgc > 74) rgc = 74;
        loff[q] = rgc * 1024 + bb * 8;      // constant per-lane ws offset
    }

    // W1h A-fragments, scaled by -log2e (rows >=300, k>=300 zeroed)
    bf16x8 afrag[3][10];
    #pragma unroll
    for (int q = 0; q < 3; ++q) {
        #pragma unroll
        for (int kt = 0; kt < 10; ++kt) {
            bool qa = (q < 2) || w4;
            int tile = w4 ? (3 * w + q) : (12 + 2 * (w - 4) + q);
            int r = tile * 16 + ln;
            int k0 = kt * 32 + lg * 8;
            uint4 p = load8_cvt_s(W1 + (size_t)r * 600 + 300 + k0,
                                  qa && r < 300, 300 - k0, NL2E);
            union { uint4 u; bf16x8 s; } cv; cv.u = p;
            afrag[q][kt] = cv.s;
        }
    }

    for (int i = tid; i < 10 * 64 * 8; i += 512) hlds[0][i] = 0;

    // uniform time pointers (per parity), advanced 2 steps per pair
    char* HWT0 = hws;            // even steps t = 0,2,...
    char* HWT1 = hws + 76800;    // odd steps  t = 1,3,...

    uint2 AS0[3], AS1[3];
    #pragma unroll
    for (int q = 0; q < 3; ++q)
        if (QOK(q)) {
            AS0[q] = *(const uint2*)(HWT0 + loff[q]);   // A'(0)
            AS1[q] = *(const uint2*)(HWT1 + loff[q]);   // A'(1)
        }
    __syncthreads();

    for (int t2 = 0; t2 < T_; t2 += 2) {
        K2W_STEP(0, t2,     AS0, HWT0)
        K2W_STEP(1, t2 + 1, AS1, HWT1)
    }
}

// ---------------------------------------------------------------------------
// K3-T2: out[b][t][n] = sum_r h_T4[t][r][b]*W2[n][r] + b2[n]; 2 t/block.
// ---------------------------------------------------------------------------
__global__ __launch_bounds__(512) void gemm_out_t2(
    const char* __restrict__ hws, const float* __restrict__ W2,
    const float* __restrict__ b2, float* __restrict__ out)
{
    __shared__ unsigned short ahs[2][8 * 132 * 4];
    __shared__ unsigned short blds[19 * 64 * 8];
    const int tid = threadIdx.x;
    const int w = tid >> 6, l = tid & 63, lg = l >> 4, ln = l & 15;
    const int th = w >> 2, wb = w & 3;
    const int t = blockIdx.x * 2 + th;

    f32x4 acc[2][19];
    #pragma unroll
    for (int q = 0; q < 2; ++q)
        #pragma unroll
        for (int nt = 0; nt < 19; ++nt) acc[q][nt] = (f32x4){0.f,0.f,0.f,0.f};

    for (int kt = 0; kt < 10; ++kt) {
        const int kc = kt * 32;
        __syncthreads();
        #pragma unroll
        for (int tt = 0; tt < 2; ++tt) {
            const char* hbase = hws + (size_t)(blockIdx.x * 2 + tt) * 76800;
            #pragma unroll
            for (int it = 0; it < 2; ++it) {
                int e = tid + it * 512;
                int rg = e >> 7, b = e & 127;
                int rgg = kt * 8 + rg;
                uint2 v = make_uint2(0u, 0u);
                if (rgg < 75) v = *(const uint2*)(hbase + (size_t)rgg * 1024 + b * 8);
                *(uint2*)&ahs[tt][(rg * 132 + b) * 4] = v;
            }
        }
        #pragma unroll
        for (int rep = 0; rep < 3; ++rep) {
            int e = tid + rep * 512;
            if (e < 1216) {
                int nn = e >> 2, kh = e & 3;
                int k0 = kc + kh * 8;
                uint4 p = load8_cvt(W2 + (size_t)nn * 300 + k0, nn < 300, 300 - k0);
                *(uint4*)&blds[(((nn >> 4) * 64) + kh * 16 + (nn & 15)) * 8] = p;
            }
        }
        __syncthreads();
        bf16x8 bfr[19];
        #pragma unroll
        for (int nt = 0; nt < 19; ++nt) bfr[nt] = *(const bf16x8*)&blds[(nt * 64 + l) * 8];
        #pragma unroll
        for (int q = 0; q < 2; ++q) {
            int b = (wb * 2 + q) * 16 + ln;
            uint2 u0 = *(const uint2*)&ahs[th][((2 * lg)     * 132 + b) * 4];
            uint2 u1 = *(const uint2*)&ahs[th][((2 * lg + 1) * 132 + b) * 4];
            union { uint4 u; bf16x8 s; } cv;
            cv.u.x = u0.x; cv.u.y = u0.y; cv.u.z = u1.x; cv.u.w = u1.y;
            bf16x8 afr = cv.s;
            #pragma unroll
            for (int nt = 0; nt < 19; ++nt)
                acc[q][nt] = __builtin_amdgcn_mfma_f32_16x16x32_bf16(afr, bfr[nt], acc[q][nt], 0, 0, 0);
        }
    }

    #pragma unroll
    for (int q = 0; q < 2; ++q)
        #pragma unroll
        for (int nt = 0; nt < 19; ++nt) {
            int n = nt * 16 + ln;
            if (n < 300) {
                float bias = b2[n];
                int b0r = (wb * 2 + q) * 16 + lg * 4;
                #pragma unroll
                for (int i = 0; i < 4; ++i)
                    out[((size_t)(b0r + i) * T_ + t) * 300 + n] = acc[q][nt][i] + bias;
            }
        }
}

// ---------------------------------------------------------------------------
// FALLBACK path (small ws): R9 kernels, unchanged.
// ---------------------------------------------------------------------------
__global__ __launch_bounds__(256) void gemm_in(
    const float* __restrict__ X, const float* __restrict__ W1,
    const float* __restrict__ b1, float* __restrict__ A)
{
    __shared__ unsigned short alds[8 * 64 * 8];
    __shared__ unsigned short blds[10 * 64 * 8];
    const int tid = threadIdx.x;
    const int w = tid >> 6, l = tid & 63, lg = l >> 4, ln = l & 15;
    const size_t m0 = (size_t)blockIdx.x * 128;
    const int n0 = blockIdx.y * 160;

    f32x4 acc[2][10];
    #pragma unroll
    for (int q = 0; q < 2; ++q)
        #pragma unroll
        for (int nt = 0; nt < 10; ++nt) acc[q][nt] = (f32x4){0.f,0.f,0.f,0.f};

    for (int kt = 0; kt < 10; ++kt) {
        const int kc = kt * 32;
        __syncthreads();
        #pragma unroll
        for (int rep = 0; rep < 2; ++rep) {
            int e = tid + rep * 256;
            int row = e >> 2, kh = e & 3;
            int k0 = kc + kh * 8;
            uint4 p = load8_cvt(X + (m0 + row) * 300 + k0, true, 300 - k0);
            *(uint4*)&alds[(((row >> 4) * 64) + kh * 16 + (row & 15)) * 8] = p;
        }
        #pragma unroll
        for (int rep = 0; rep < 3; ++rep) {
            int e = tid + rep * 256;
            if (e < 640) {
                int nn = e >> 2, kh = e & 3;
                int n = n0 + nn;
                int k0 = kc + kh * 8;
                uint4 p = load8_cvt(W1 + (size_t)n * 600 + k0, n < 300, 300 - k0);
                *(uint4*)&blds[(((nn >> 4) * 64) + kh * 16 + (nn & 15)) * 8] = p;
            }
        }
        __syncthreads();
        bf16x8 bfr[10];
        #pragma unroll
        for (int nt = 0; nt < 10; ++nt) bfr[nt] = *(const bf16x8*)&blds[(nt * 64 + l) * 8];
        #pragma unroll
        for (int q = 0; q < 2; ++q) {
            bf16x8 afr = *(const bf16x8*)&alds[((w * 2 + q) * 64 + l) * 8];
            #pragma unroll
            for (int nt = 0; nt < 10; ++nt)
                acc[q][nt] = __builtin_amdgcn_mfma_f32_16x16x32_bf16(afr, bfr[nt], acc[q][nt], 0, 0, 0);
        }
    }

    #pragma unroll
    for (int q = 0; q < 2; ++q)
        #pragma unroll
        for (int nt = 0; nt < 10; ++nt) {
            int n = n0 + nt * 16 + ln;
            if (n < 300) {
                float bias = b1[n];
                size_t mr = m0 + (w * 2 + q) * 16 + lg * 4;
                #pragma unroll
                for (int i = 0; i < 4; ++i)
                    A[(mr + i) * 300 + n] = (acc[q][nt][i] + bias) * NL2E;
            }
        }
}

#define K2_STEP(P, tval, ASLOT, APTR, HPME, HPOTHER)                            \
    {                                                                           \
        const int t = (tval);                                                   \
        const int tt = t - 1;                                                   \
        const size_t so = (size_t)(tt >> 6) * 76800 + (size_t)(tt & 63) * 600;  \
        bf16x8 bfr[10];                                                         \
        _Pragma("unroll")                                                       \
        for (int kt = 0; kt < 10; ++kt)                                         \
            bfr[kt] = *(const bf16x8*)&hlds[P][(kt * 64 + l) * 8];              \
        f32x4 acc[3], accB[3];                                                  \
        _Pragma("unroll")                                                       \
        for (int q = 0; q < 3; ++q) {                                           \
            acc[q] = QOK(q) ? ASLOT[q] : (f32x4){0.f,0.f,0.f,0.f};              \
            accB[q] = (f32x4){0.f,0.f,0.f,0.f};                                 \
        }                                                                       \
        _Pragma("unroll")                                                       \
        for (int q = 0; q < 3; ++q)                                             \
            if (QOK(q)) ASLOT[q] = *(const f32x4*)(APTR + rq[q] * 4);           \
        APTR += 2400;                                                           \
        __builtin_amdgcn_s_setprio(1);                                          \
        _Pragma("unroll")                                                       \
        for (int kt = 0; kt < 5; ++kt) {                                        \
            acc[0]  = __builtin_amdgcn_mfma_f32_16x16x32_bf16(afrag[0][kt],   bfr[kt],   acc[0],  0, 0, 0); \
            accB[0] = __builtin_amdgcn_mfma_f32_16x16x32_bf16(afrag[0][kt+5], bfr[kt+5], accB[0], 0, 0, 0); \
            acc[1]  = __builtin_amdgcn_mfma_f32_16x16x32_bf16(afrag[1][kt],   bfr[kt],   acc[1],  0, 0, 0); \
            accB[1] = __builtin_amdgcn_mfma_f32_16x16x32_bf16(afrag[1][kt+5], bfr[kt+5], accB[1], 0, 0, 0); \
            if (w4) {                                                           \
                acc[2]  = __builtin_amdgcn_mfma_f32_16x16x32_bf16(afrag[2][kt],   bfr[kt],   acc[2],  0, 0, 0); \
                accB[2] = __builtin_amdgcn_mfma_f32_16x16x32_bf16(afrag[2][kt+5], bfr[kt+5], accB[2], 0, 0, 0); \
            }                                                                   \
        }                                                                       \
        __builtin_amdgcn_s_setprio(0);                                          \
        _Pragma("unroll")                                                       \
        for (int q = 0; q < 3; ++q) {                                           \
            if (!QOK(q)) continue;                                              \
            f32x4 hv;                                                           \
            _Pragma("unroll")                                                   \
            for (int i = 0; i < 4; ++i) {                                       \
                float zn = acc[q][i] + accB[q][i];                              \
                float ex, sg;                                                   \
                asm("v_exp_f32 %0, %1" : "=v"(ex) : "v"(zn));                   \
                asm("v_rcp_f32 %0, %1" : "=v"(sg) : "v"(1.0f + ex));            \
                hv[i] = sg;                                                     \
            }                                                                   \
            unsigned plo, phi;                                                  \
            asm("v_cvt_pk_bf16_f32 %0, %1, %2" : "=v"(plo) : "v"(hv[0]), "v"(hv[1])); \
            asm("v_cvt_pk_bf16_f32 %0, %1, %2" : "=v"(phi) : "v"(hv[2]), "v"(hv[3])); \
            HPME[q].x = plo; HPME[q].y = phi;                                   \
            *(uint2*)((char*)hlds + ((P) ^ 1) * 10240 + ldsoff[q]) = HPME[q];   \
            if (t > 0 && rq[q] < 300)                                           \
                *(uint2*)(sbase + so + rq[q] * 2) = HPOTHER[q];                 \
        }                                                                       \
        asm volatile("s_waitcnt lgkmcnt(0)" ::: "memory");                      \
        __builtin_amdgcn_s_barrier();                                           \
        asm volatile("" ::: "memory");                                          \
    }

__global__ __launch_bounds__(512) void elman_rec_mfma(
    const float* __restrict__ W1, float* __restrict__ buf,
    float* __restrict__ hfinal)
{
    __shared__ unsigned short hlds[2][10 * 64 * 8];
    const int tid = threadIdx.x;
    const int w = tid >> 6, l = tid & 63, lg = l >> 4, ln = l & 15;
    const bool w4 = (w < 4);
    const int bb = blockIdx.x * 16 + ln;

    int rq[3], ldsoff[3];
    #pragma unroll
    for (int q = 0; q < 3; ++q) {
        int tile = w4 ? (3 * w + q) : (12 + 2 * (w - 4) + q);
        int r = tile * 16 + 4 * lg;
        rq[q] = r;
        ldsoff[q] = (((r >> 5) * 64 + ((r >> 3) & 3) * 16 + ln) * 8 + (r & 7)) * 2;
    }

    bf16x8 afrag[3][10];
    #pragma unroll
    for (int q = 0; q < 3; ++q) {
        #pragma unroll
        for (int kt = 0; kt < 10; ++kt) {
            bool qa = (q < 2) || w4;
            int tile = w4 ? (3 * w + q) : (12 + 2 * (w - 4) + q);
            int r = tile * 16 + ln;
            int k0 = kt * 32 + lg * 8;
            uint4 p = load8_cvt_s(W1 + (size_t)r * 600 + 300 + k0,
                                  qa && r < 300, 300 - k0, NL2E);
            union { uint4 u; bf16x8 s; } cv; cv.u = p;
            afrag[q][kt] = cv.s;
        }
    }

    for (int i = tid; i < 10 * 64 * 8; i += 512) hlds[0][i] = 0;

    const char* abase = (const char*)(buf + (size_t)bb * T_ * 300);
    char* sbase = (char*)buf + (size_t)bb * 16 * 76800;

    f32x4 A0[3], A1[3];
    #pragma unroll
    for (int q = 0; q < 3; ++q)
        if (QOK(q)) {
            A0[q] = *(const f32x4*)(abase + rq[q] * 4);
            A1[q] = *(const f32x4*)(abase + 1200 + rq[q] * 4);
        }
    const char* aptr0 = abase + 2400;
    const char* aptr1 = abase + 3600;
    uint2 hpA[3], hpB[3];
    __syncthreads();

    for (int t2 = 0; t2 < T_; t2 += 2) {
        K2_STEP(0, t2,     A0, aptr0, hpA, hpB)
        K2_STEP(1, t2 + 1, A1, aptr1, hpB, hpA)
    }

    {
        const int tt = T_ - 1;
        const size_t so = (size_t)(tt >> 6) * 76800 + (size_t)(tt & 63) * 600;
        #pragma unroll
        for (int q = 0; q < 3; ++q)
            if (QOK(q) && rq[q] < 300) {
                *(uint2*)(sbase + so + rq[q] * 2) = hpB[q];
                f32x4 hv;
                union { float f; unsigned u; } c0, c1, c2, c3;
                c0.u = hpB[q].x << 16; c1.u = hpB[q].x & 0xFFFF0000u;
                c2.u = hpB[q].y << 16; c3.u = hpB[q].y & 0xFFFF0000u;
                hv[0] = c0.f; hv[1] = c1.f; hv[2] = c2.f; hv[3] = c3.f;
                *(f32x4*)(hfinal + bb * 300 + rq[q]) = hv;
            }
    }
}

__global__ __launch_bounds__(256) void gemm_out(
    float* __restrict__ buf, const float* __restrict__ W2,
    const float* __restrict__ b2)
{
    __shared__ unsigned short alds[4 * 64 * 8];
    __shared__ unsigned short blds[19 * 64 * 8];
    const int tid = threadIdx.x;
    const int w = tid >> 6, l = tid & 63, lg = l >> 4, ln = l & 15;
    const size_t chunk = blockIdx.x;
    const char* pbase = (const char*)buf + chunk * 76800;

    f32x4 acc[19];
    #pragma unroll
    for (int nt = 0; nt < 19; ++nt) acc[nt] = (f32x4){0.f,0.f,0.f,0.f};

    for (int kt = 0; kt < 10; ++kt) {
        const int kc = kt * 32;
        __syncthreads();
        {
            int row = tid >> 2, kh = tid & 3;
            int k0 = kc + kh * 8;
            const char* p = pbase + row * 600;
            uint2 lo = make_uint2(0u, 0u), hi = make_uint2(0u, 0u);
            int krem = 300 - k0;
            if (krem >= 8)      { lo = *(const uint2*)(p + k0 * 2); hi = *(const uint2*)(p + k0 * 2 + 8); }
            else if (krem >= 4) { lo = *(const uint2*)(p + k0 * 2); }
            uint4 pk; pk.x = lo.x; pk.y = lo.y; pk.z = hi.x; pk.w = hi.y;
            *(uint4*)&alds[(((row >> 4) * 64) + kh * 16 + (row & 15)) * 8] = pk;
        }
        #pragma unroll
        for (int rep = 0; rep < 5; ++rep) {
            int e = tid + rep * 256;
            if (e < 1216) {
                int nn = e >> 2, kh = e & 3;
                int k0 = kc + kh * 8;
                uint4 p = load8_cvt(W2 + (size_t)nn * 300 + k0, nn < 300, 300 - k0);
                *(uint4*)&blds[(((nn >> 4) * 64) + kh * 16 + (nn & 15)) * 8] = p;
            }
        }
        __syncthreads();
        bf16x8 afr = *(const bf16x8*)&alds[(w * 64 + l) * 8];
        #pragma unroll
        for (int nt = 0; nt < 19; ++nt) {
            bf16x8 bfr = *(const bf16x8*)&blds[(nt * 64 + l) * 8];
            acc[nt] = __builtin_amdgcn_mfma_f32_16x16x32_bf16(afr, bfr, acc[nt], 0, 0, 0);
        }
    }

    float* frow = buf + chunk * 19200;
    #pragma unroll
    for (int nt = 0; nt < 19; ++nt) {
        int n = nt * 16 + ln;
        if (n < 300) {
            float bias = b2[n];
            int mr = w * 16 + lg * 4;
            #pragma unroll
            for (int i = 0; i < 4; ++i)
                frow[(mr + i) * 300 + n] = acc[nt][i] + bias;
        }
    }
}

// ---------------------------------------------------------------------------
extern "C" void kernel_launch(void* const* d_in, const int* in_sizes, int n_in,
                              void* d_out, int out_size, void* d_ws, size_t ws_size,
                              hipStream_t stream)
{
    const float* x  = (const float*)d_in[0];
    const float* W1 = (const float*)d_in[1];
    const float* b1 = (const float*)d_in[2];
    const float* W2 = (const float*)d_in[3];
    const float* b2 = (const float*)d_in[4];

    float* out    = (float*)d_out;
    float* hfinal = out + (size_t)HB;

    const size_t HT4 = (size_t)T_ * 75 * 128 * 8;   // 78,643,200 B
    if (ws_size >= HT4 + 2 * 76800) {               // + prefetch overrun slack
        gemm_in_t2<<<512, 512, 0, stream>>>(x, W1, b1, (char*)d_ws);
        elman_rec_ws<<<8, 512, 0, stream>>>(W1, hfinal, (char*)d_ws);
        gemm_out_t2<<<512, 512, 0, stream>>>((const char*)d_ws, W2, b2, out);
    } else {
        gemm_in<<<dim3(1024, 2), 256, 0, stream>>>(x, W1, b1, out);
        elman_rec_mfma<<<8, 512, 0, stream>>>(W1, out, hfinal);
        gemm_out<<<2048, 256, 0, stream>>>(out, W2, b2);
    }
}

// Round 16
// 979.014 us; speedup vs baseline: 1.3223x; 1.0125x over previous
//
#include <hip/hip_runtime.h>

typedef __attribute__((ext_vector_type(4))) float f32x4;
typedef __attribute__((ext_vector_type(8))) short bf16x8;

#define B_   128
#define T_   1024
#define NROW 131072      // B*T
#define HB   (NROW*300)  // floats in the [B*T][300] matrix
#define NL2E -1.44269504088896340736f   // -log2(e)

#define HT4   ((size_t)T_ * 75 * 128 * 8)          // 78,643,200 B (h_T4)
#define WOFF  (HT4 + 2 * 76800)                    // prefetch-overrun slack end
#define WSZ1  194560                               // 10 kt * 19456 B per W

__device__ inline unsigned short f2bf(float f) {
    union { float f; unsigned int u; } v; v.f = f;
    unsigned int r = v.u + 0x7FFFu + ((v.u >> 16) & 1u);
    return (unsigned short)(r >> 16);
}

__device__ inline uint4 load8_cvt_s(const float* src, bool rowok, int krem, float scale) {
    f32x4 v0 = {0.f,0.f,0.f,0.f}, v1 = {0.f,0.f,0.f,0.f};
    if (rowok) {
        if (krem >= 8)      { v0 = *(const f32x4*)src; v1 = *(const f32x4*)(src + 4); }
        else if (krem >= 4) { v0 = *(const f32x4*)src; }
    }
    v0 *= scale; v1 *= scale;
    uint4 p;
    p.x = (unsigned)f2bf(v0[0]) | ((unsigned)f2bf(v0[1]) << 16);
    p.y = (unsigned)f2bf(v0[2]) | ((unsigned)f2bf(v0[3]) << 16);
    p.z = (unsigned)f2bf(v1[0]) | ((unsigned)f2bf(v1[1]) << 16);
    p.w = (unsigned)f2bf(v1[2]) | ((unsigned)f2bf(v1[3]) << 16);
    return p;
}

__device__ inline uint4 load8_cvt(const float* src, bool rowok, int krem) {
    return load8_cvt_s(src, rowok, krem, 1.0f);
}

// ---------------------------------------------------------------------------
// K0: one-time W conversion into frag-linear bf16 in ws tail.
// blocks 0-9: W1x (NL2E-scaled), kt=blockIdx; blocks 10-19: W2, kt=blockIdx-10.
// Layout matches the per-kt LDS frag-linear layout so staging is a linear copy.
// ---------------------------------------------------------------------------
__global__ __launch_bounds__(256) void convert_w(
    const float* __restrict__ W1, const float* __restrict__ W2,
    char* __restrict__ wsbase)
{
    const int kt = blockIdx.x % 10;
    const bool isW2 = blockIdx.x >= 10;
    char* dst = wsbase + (isW2 ? WSZ1 : 0) + (size_t)kt * 19456;
    #pragma unroll
    for (int rep = 0; rep < 5; ++rep) {
        int e = threadIdx.x + rep * 256;
        if (e < 1216) {
            int nn = e >> 2, kh = e & 3, k0 = kt * 32 + kh * 8;
            uint4 p = isW2
                ? load8_cvt(W2 + (size_t)nn * 300 + k0, nn < 300, 300 - k0)
                : load8_cvt_s(W1 + (size_t)nn * 600 + k0, nn < 300, 300 - k0, NL2E);
            int perm = ((nn >> 4) * 64) + (kh * 16) + (nn & 15);
            *(uint4*)(dst + (size_t)perm * 16) = p;
        }
    }
}

// ---------------------------------------------------------------------------
// K1-T2b (ws path): A'_T4[t][rg][b][4 bf16] time-major into ws; 2 t/block.
// W1x tile staged as a plain linear uint4 copy from pre-converted bf16.
// ---------------------------------------------------------------------------
__global__ __launch_bounds__(512) void gemm_in_t2b(
    const float* __restrict__ X, const char* __restrict__ wbf1,
    const float* __restrict__ b1, char* __restrict__ aws)
{
    __shared__ unsigned short wlds[19 * 64 * 8];
    __shared__ unsigned short xlds[2][8 * 64 * 8];
    const int tid = threadIdx.x;
    const int w = tid >> 6, l = tid & 63, lg = l >> 4, ln = l & 15;
    const int th = w >> 2, wb = w & 3;
    const int t = blockIdx.x * 2 + th;

    f32x4 acc[2][19];
    #pragma unroll
    for (int q = 0; q < 2; ++q)
        #pragma unroll
        for (int mt = 0; mt < 19; ++mt) acc[q][mt] = (f32x4){0.f,0.f,0.f,0.f};

    for (int kt = 0; kt < 10; ++kt) {
        const int kc = kt * 32;
        __syncthreads();
        // stage W1x tile: linear bf16 copy (no cvt VALU)
        {
            const uint4* wsrc = (const uint4*)(wbf1 + (size_t)kt * 19456);
            #pragma unroll
            for (int rep = 0; rep < 3; ++rep) {
                int e = tid + rep * 512;
                if (e < 1216) *(uint4*)&wlds[e * 8] = wsrc[e];
            }
        }
        // stage x tiles for both t (needs cvt)
        #pragma unroll
        for (int tt = 0; tt < 2; ++tt) {
            int e = tid;
            int row = e >> 2, kh = e & 3;
            int k0 = kc + kh * 8;
            uint4 p = load8_cvt(X + ((size_t)row * 1024 + blockIdx.x * 2 + tt) * 300 + k0,
                                true, 300 - k0);
            *(uint4*)&xlds[tt][(((row >> 4) * 64) + kh * 16 + (row & 15)) * 8] = p;
        }
        __syncthreads();
        bf16x8 wfr[19];
        #pragma unroll
        for (int mt = 0; mt < 19; ++mt) wfr[mt] = *(const bf16x8*)&wlds[(mt * 64 + l) * 8];
        #pragma unroll
        for (int q = 0; q < 2; ++q) {
            bf16x8 xfr = *(const bf16x8*)&xlds[th][((wb * 2 + q) * 64 + l) * 8];
            #pragma unroll
            for (int mt = 0; mt < 19; ++mt)
                acc[q][mt] = __builtin_amdgcn_mfma_f32_16x16x32_bf16(wfr[mt], xfr, acc[q][mt], 0, 0, 0);
        }
    }

    char* tb = aws + (size_t)t * 76800;
    #pragma unroll
    for (int q = 0; q < 2; ++q) {
        int b = (wb * 2 + q) * 16 + ln;
        #pragma unroll
        for (int mt = 0; mt < 19; ++mt) {
            int rg = mt * 4 + lg;
            if (rg < 75) {
                f32x4 bias = *(const f32x4*)(b1 + mt * 16 + lg * 4);
                float v0 = acc[q][mt][0] + bias[0] * NL2E;
                float v1 = acc[q][mt][1] + bias[1] * NL2E;
                float v2 = acc[q][mt][2] + bias[2] * NL2E;
                float v3 = acc[q][mt][3] + bias[3] * NL2E;
                unsigned plo, phi;
                asm("v_cvt_pk_bf16_f32 %0, %1, %2" : "=v"(plo) : "v"(v0), "v"(v1));
                asm("v_cvt_pk_bf16_f32 %0, %1, %2" : "=v"(phi) : "v"(v2), "v"(v3));
                uint2 pk; pk.x = plo; pk.y = phi;
                *(uint2*)(tb + (size_t)rg * 1024 + b * 8) = pk;
            }
        }
    }
}

#define QOK(q) ((q) < 2 || w4)

// ---------------------------------------------------------------------------
// K2-WS3 (best known): recurrence; A'/h in ws time-major (h(t) overwrites
// A'(t) in place; race-free). 8 blocks x 512 thr. Per-q MFMA/sigmoid
// interleave; uniform time pointer + constant lane offsets; exp2 sigmoid;
// one lgkmcnt(0)+s_barrier per step.
// ---------------------------------------------------------------------------
#define K2_CHAIN(q)                                                             \
    _Pragma("unroll")                                                           \
    for (int kt = 0; kt < 5; ++kt) {                                            \
        acc[q]  = __builtin_amdgcn_mfma_f32_16x16x32_bf16(afrag[q][kt],   bfr[kt],   acc[q],  0, 0, 0); \
        accB[q] = __builtin_amdgcn_mfma_f32_16x16x32_bf16(afrag[q][kt+5], bfr[kt+5], accB[q], 0, 0, 0); \
    }

#define K2_SIG(q, P, HWT, t)                                                    \
    {                                                                           \
        f32x4 hv;                                                               \
        _Pragma("unroll")                                                       \
        for (int i = 0; i < 4; ++i) {                                           \
            float zn = acc[q][i] + accB[q][i];      /* = -z*log2e */            \
            float ex, sg;                                                       \
            asm("v_exp_f32 %0, %1" : "=v"(ex) : "v"(zn));                       \
            asm("v_rcp_f32 %0, %1" : "=v"(sg) : "v"(1.0f + ex));                \
            hv[i] = sg;                                                         \
        }                                                                       \
        unsigned plo, phi;                                                      \
        asm("v_cvt_pk_bf16_f32 %0, %1, %2" : "=v"(plo) : "v"(hv[0]), "v"(hv[1])); \
        asm("v_cvt_pk_bf16_f32 %0, %1, %2" : "=v"(phi) : "v"(hv[2]), "v"(hv[3])); \
        uint2 pk; pk.x = plo; pk.y = phi;                                       \
        *(uint2*)((char*)hlds + ((P) ^ 1) * 10240 + ldsoff[q]) = pk;            \
        if (rq[q] < 300) {                                                      \
            *(uint2*)((HWT) + loff[q]) = pk;    /* h(t) overwrites A'(t) */     \
            if ((t) == T_ - 1)                                                  \
                *(f32x4*)(hfinal + bb * 300 + rq[q]) = hv;                      \
        }                                                                       \
    }

#define K2W_STEP(P, tval, AS, HWT)                                              \
    {                                                                           \
        const int t = (tval);                                                   \
        bf16x8 bfr[10];                                                         \
        _Pragma("unroll")                                                       \
        for (int kt = 0; kt < 10; ++kt)                                         \
            bfr[kt] = *(const bf16x8*)&hlds[P][(kt * 64 + l) * 8];              \
        f32x4 acc[3], accB[3];                                                  \
        _Pragma("unroll")                                                       \
        for (int q = 0; q < 3; ++q) {                                           \
            union { float f; unsigned u; } u0, u1, u2, u3;                      \
            u0.u = AS[q].x << 16; u1.u = AS[q].x & 0xFFFF0000u;                 \
            u2.u = AS[q].y << 16; u3.u = AS[q].y & 0xFFFF0000u;                 \
            acc[q] = (f32x4){u0.f, u1.f, u2.f, u3.f};                           \
            accB[q] = (f32x4){0.f,0.f,0.f,0.f};                                 \
        }                                                                       \
        /* prefetch A'(t+2): uniform base + const lane offset */                \
        _Pragma("unroll")                                                       \
        for (int q = 0; q < 3; ++q)                                             \
            if (QOK(q)) AS[q] = *(const uint2*)((HWT) + 153600 + loff[q]);      \
        __builtin_amdgcn_s_setprio(1);                                          \
        K2_CHAIN(0)                                                             \
        K2_CHAIN(1)                                                             \
        __builtin_amdgcn_s_setprio(0);                                          \
        K2_SIG(0, P, HWT, t)                                                    \
        if (w4) {                                                               \
            __builtin_amdgcn_s_setprio(1);                                      \
            K2_CHAIN(2)                                                         \
            __builtin_amdgcn_s_setprio(0);                                      \
        }                                                                       \
        K2_SIG(1, P, HWT, t)                                                    \
        if (w4) K2_SIG(2, P, HWT, t)                                            \
        HWT += 153600;                                                          \
        asm volatile("s_waitcnt lgkmcnt(0)" ::: "memory");                      \
        __builtin_amdgcn_s_barrier();                                           \
        asm volatile("" ::: "memory");                                          \
    }

__global__ __launch_bounds__(512) void elman_rec_ws(
    const float* __restrict__ W1, float* __restrict__ hfinal,
    char* __restrict__ hws)
{
    __shared__ unsigned short hlds[2][10 * 64 * 8];   // 2 x 10240 B
    const int tid = threadIdx.x;
    const int w = tid >> 6, l = tid & 63, lg = l >> 4, ln = l & 15;
    const bool w4 = (w < 4);
    const int bb = blockIdx.x * 16 + ln;    // this lane's batch (B/C column)

    int rq[3], ldsoff[3], loff[3];
    #pragma unroll
    for (int q = 0; q < 3; ++q) {
        int tile = w4 ? (3 * w + q) : (12 + 2 * (w - 4) + q);
        int r = tile * 16 + 4 * lg;
        rq[q] = r;
        ldsoff[q] = (((r >> 5) * 64 + ((r >> 3) & 3) * 16 + ln) * 8 + (r & 7)) * 2;
        int rgc = r >> 2; if (rgc > 74) rgc = 74;
        loff[q] = rgc * 1024 + bb * 8;      // constant per-lane ws offset
    }

    // W1h A-fragments, scaled by -log2e (rows >=300, k>=300 zeroed)
    bf16x8 afrag[3][10];
    #pragma unroll
    for (int q = 0; q < 3; ++q) {
        #pragma unroll
        for (int kt = 0; kt < 10; ++kt) {
            bool qa = (q < 2) || w4;
            int tile = w4 ? (3 * w + q) : (12 + 2 * (w - 4) + q);
            int r = tile * 16 + ln;
            int k0 = kt * 32 + lg * 8;
            uint4 p = load8_cvt_s(W1 + (size_t)r * 600 + 300 + k0,
                                  qa && r < 300, 300 - k0, NL2E);
            union { uint4 u; bf16x8 s; } cv; cv.u = p;
            afrag[q][kt] = cv.s;
        }
    }

    for (int i = tid; i < 10 * 64 * 8; i += 512) hlds[0][i] = 0;

    // uniform time pointers (per parity), advanced 2 steps per pair
    char* HWT0 = hws;            // even steps t = 0,2,...
    char* HWT1 = hws + 76800;    // odd steps  t = 1,3,...

    uint2 AS0[3], AS1[3];
    #pragma unroll
    for (int q = 0; q < 3; ++q)
        if (QOK(q)) {
            AS0[q] = *(const uint2*)(HWT0 + loff[q]);   // A'(0)
            AS1[q] = *(const uint2*)(HWT1 + loff[q]);   // A'(1)
        }
    __syncthreads();

    for (int t2 = 0; t2 < T_; t2 += 2) {
        K2W_STEP(0, t2,     AS0, HWT0)
        K2W_STEP(1, t2 + 1, AS1, HWT1)
    }
}

// ---------------------------------------------------------------------------
// K3-T2b: out[b][t][n] = sum_r h_T4[t][r][b]*W2[n][r] + b2[n]; 2 t/block.
// W2 tile staged as a plain linear uint4 copy from pre-converted bf16.
// ---------------------------------------------------------------------------
__global__ __launch_bounds__(512) void gemm_out_t2b(
    const char* __restrict__ hws, const char* __restrict__ wbf2,
    const float* __restrict__ b2, float* __restrict__ out)
{
    __shared__ unsigned short ahs[2][8 * 132 * 4];
    __shared__ unsigned short blds[19 * 64 * 8];
    const int tid = threadIdx.x;
    const int w = tid >> 6, l = tid & 63, lg = l >> 4, ln = l & 15;
    const int th = w >> 2, wb = w & 3;
    const int t = blockIdx.x * 2 + th;

    f32x4 acc[2][19];
    #pragma unroll
    for (int q = 0; q < 2; ++q)
        #pragma unroll
        for (int nt = 0; nt < 19; ++nt) acc[q][nt] = (f32x4){0.f,0.f,0.f,0.f};

    for (int kt = 0; kt < 10; ++kt) {
        __syncthreads();
        #pragma unroll
        for (int tt = 0; tt < 2; ++tt) {
            const char* hbase = hws + (size_t)(blockIdx.x * 2 + tt) * 76800;
            #pragma unroll
            for (int it = 0; it < 2; ++it) {
                int e = tid + it * 512;
                int rg = e >> 7, b = e & 127;
                int rgg = kt * 8 + rg;
                uint2 v = make_uint2(0u, 0u);
                if (rgg < 75) v = *(const uint2*)(hbase + (size_t)rgg * 1024 + b * 8);
                *(uint2*)&ahs[tt][(rg * 132 + b) * 4] = v;
            }
        }
        // stage W2 tile: linear bf16 copy
        {
            const uint4* wsrc = (const uint4*)(wbf2 + (size_t)kt * 19456);
            #pragma unroll
            for (int rep = 0; rep < 3; ++rep) {
                int e = tid + rep * 512;
                if (e < 1216) *(uint4*)&blds[e * 8] = wsrc[e];
            }
        }
        __syncthreads();
        bf16x8 bfr[19];
        #pragma unroll
        for (int nt = 0; nt < 19; ++nt) bfr[nt] = *(const bf16x8*)&blds[(nt * 64 + l) * 8];
        #pragma unroll
        for (int q = 0; q < 2; ++q) {
            int b = (wb * 2 + q) * 16 + ln;
            uint2 u0 = *(const uint2*)&ahs[th][((2 * lg)     * 132 + b) * 4];
            uint2 u1 = *(const uint2*)&ahs[th][((2 * lg + 1) * 132 + b) * 4];
            union { uint4 u; bf16x8 s; } cv;
            cv.u.x = u0.x; cv.u.y = u0.y; cv.u.z = u1.x; cv.u.w = u1.y;
            bf16x8 afr = cv.s;
            #pragma unroll
            for (int nt = 0; nt < 19; ++nt)
                acc[q][nt] = __builtin_amdgcn_mfma_f32_16x16x32_bf16(afr, bfr[nt], acc[q][nt], 0, 0, 0);
        }
    }

    #pragma unroll
    for (int q = 0; q < 2; ++q)
        #pragma unroll
        for (int nt = 0; nt < 19; ++nt) {
            int n = nt * 16 + ln;
            if (n < 300) {
                float bias = b2[n];
                int b0r = (wb * 2 + q) * 16 + lg * 4;
                #pragma unroll
                for (int i = 0; i < 4; ++i)
                    out[((size_t)(b0r + i) * T_ + t) * 300 + n] = acc[q][nt][i] + bias;
            }
        }
}

// ---------------------------------------------------------------------------
// MIDDLE PATH (ws fits h but not W): R15 kernels with inline W conversion.
// ---------------------------------------------------------------------------
__global__ __launch_bounds__(512) void gemm_in_t2(
    const float* __restrict__ X, const float* __restrict__ W1,
    const float* __restrict__ b1, char* __restrict__ aws)
{
    __shared__ unsigned short wlds[19 * 64 * 8];
    __shared__ unsigned short xlds[2][8 * 64 * 8];
    const int tid = threadIdx.x;
    const int w = tid >> 6, l = tid & 63, lg = l >> 4, ln = l & 15;
    const int th = w >> 2, wb = w & 3;
    const int t = blockIdx.x * 2 + th;

    f32x4 acc[2][19];
    #pragma unroll
    for (int q = 0; q < 2; ++q)
        #pragma unroll
        for (int mt = 0; mt < 19; ++mt) acc[q][mt] = (f32x4){0.f,0.f,0.f,0.f};

    for (int kt = 0; kt < 10; ++kt) {
        const int kc = kt * 32;
        __syncthreads();
        #pragma unroll
        for (int rep = 0; rep < 3; ++rep) {
            int e = tid + rep * 512;
            if (e < 1216) {
                int nn = e >> 2, kh = e & 3;
                int k0 = kc + kh * 8;
                uint4 p = load8_cvt_s(W1 + (size_t)nn * 600 + k0, nn < 300, 300 - k0, NL2E);
                *(uint4*)&wlds[(((nn >> 4) * 64) + kh * 16 + (nn & 15)) * 8] = p;
            }
        }
        #pragma unroll
        for (int tt = 0; tt < 2; ++tt) {
            int e = tid;
            int row = e >> 2, kh = e & 3;
            int k0 = kc + kh * 8;
            uint4 p = load8_cvt(X + ((size_t)row * 1024 + blockIdx.x * 2 + tt) * 300 + k0,
                                true, 300 - k0);
            *(uint4*)&xlds[tt][(((row >> 4) * 64) + kh * 16 + (row & 15)) * 8] = p;
        }
        __syncthreads();
        bf16x8 wfr[19];
        #pragma unroll
        for (int mt = 0; mt < 19; ++mt) wfr[mt] = *(const bf16x8*)&wlds[(mt * 64 + l) * 8];
        #pragma unroll
        for (int q = 0; q < 2; ++q) {
            bf16x8 xfr = *(const bf16x8*)&xlds[th][((wb * 2 + q) * 64 + l) * 8];
            #pragma unroll
            for (int mt = 0; mt < 19; ++mt)
                acc[q][mt] = __builtin_amdgcn_mfma_f32_16x16x32_bf16(wfr[mt], xfr, acc[q][mt], 0, 0, 0);
        }
    }

    char* tb = aws + (size_t)t * 76800;
    #pragma unroll
    for (int q = 0; q < 2; ++q) {
        int b = (wb * 2 + q) * 16 + ln;
        #pragma unroll
        for (int mt = 0; mt < 19; ++mt) {
            int rg = mt * 4 + lg;
            if (rg < 75) {
                f32x4 bias = *(const f32x4*)(b1 + mt * 16 + lg * 4);
                float v0 = acc[q][mt][0] + bias[0] * NL2E;
                float v1 = acc[q][mt][1] + bias[1] * NL2E;
                float v2 = acc[q][mt][2] + bias[2] * NL2E;
                float v3 = acc[q][mt][3] + bias[3] * NL2E;
                unsigned plo, phi;
                asm("v_cvt_pk_bf16_f32 %0, %1, %2" : "=v"(plo) : "v"(v0), "v"(v1));
                asm("v_cvt_pk_bf16_f32 %0, %1, %2" : "=v"(phi) : "v"(v2), "v"(v3));
                uint2 pk; pk.x = plo; pk.y = phi;
                *(uint2*)(tb + (size_t)rg * 1024 + b * 8) = pk;
            }
        }
    }
}

__global__ __launch_bounds__(512) void gemm_out_t2(
    const char* __restrict__ hws, const float* __restrict__ W2,
    const float* __restrict__ b2, float* __restrict__ out)
{
    __shared__ unsigned short ahs[2][8 * 132 * 4];
    __shared__ unsigned short blds[19 * 64 * 8];
    const int tid = threadIdx.x;
    const int w = tid >> 6, l = tid & 63, lg = l >> 4, ln = l & 15;
    const int th = w >> 2, wb = w & 3;
    const int t = blockIdx.x * 2 + th;

    f32x4 acc[2][19];
    #pragma unroll
    for (int q = 0; q < 2; ++q)
        #pragma unroll
        for (int nt = 0; nt < 19; ++nt) acc[q][nt] = (f32x4){0.f,0.f,0.f,0.f};

    for (int kt = 0; kt < 10; ++kt) {
        const int kc = kt * 32;
        __syncthreads();
        #pragma unroll
        for (int tt = 0; tt < 2; ++tt) {
            const char* hbase = hws + (size_t)(blockIdx.x * 2 + tt) * 76800;
            #pragma unroll
            for (int it = 0; it < 2; ++it) {
                int e = tid + it * 512;
                int rg = e >> 7, b = e & 127;
                int rgg = kt * 8 + rg;
                uint2 v = make_uint2(0u, 0u);
                if (rgg < 75) v = *(const uint2*)(hbase + (size_t)rgg * 1024 + b * 8);
                *(uint2*)&ahs[tt][(rg * 132 + b) * 4] = v;
            }
        }
        #pragma unroll
        for (int rep = 0; rep < 3; ++rep) {
            int e = tid + rep * 512;
            if (e < 1216) {
                int nn = e >> 2, kh = e & 3;
                int k0 = kc + kh * 8;
                uint4 p = load8_cvt(W2 + (size_t)nn * 300 + k0, nn < 300, 300 - k0);
                *(uint4*)&blds[(((nn >> 4) * 64) + kh * 16 + (nn & 15)) * 8] = p;
            }
        }
        __syncthreads();
        bf16x8 bfr[19];
        #pragma unroll
        for (int nt = 0; nt < 19; ++nt) bfr[nt] = *(const bf16x8*)&blds[(nt * 64 + l) * 8];
        #pragma unroll
        for (int q = 0; q < 2; ++q) {
            int b = (wb * 2 + q) * 16 + ln;
            uint2 u0 = *(const uint2*)&ahs[th][((2 * lg)     * 132 + b) * 4];
            uint2 u1 = *(const uint2*)&ahs[th][((2 * lg + 1) * 132 + b) * 4];
            union { uint4 u; bf16x8 s; } cv;
            cv.u.x = u0.x; cv.u.y = u0.y; cv.u.z = u1.x; cv.u.w = u1.y;
            bf16x8 afr = cv.s;
            #pragma unroll
            for (int nt = 0; nt < 19; ++nt)
                acc[q][nt] = __builtin_amdgcn_mfma_f32_16x16x32_bf16(afr, bfr[nt], acc[q][nt], 0, 0, 0);
        }
    }

    #pragma unroll
    for (int q = 0; q < 2; ++q)
        #pragma unroll
        for (int nt = 0; nt < 19; ++nt) {
            int n = nt * 16 + ln;
            if (n < 300) {
                float bias = b2[n];
                int b0r = (wb * 2 + q) * 16 + lg * 4;
                #pragma unroll
                for (int i = 0; i < 4; ++i)
                    out[((size_t)(b0r + i) * T_ + t) * 300 + n] = acc[q][nt][i] + bias;
            }
        }
}

// ---------------------------------------------------------------------------
// FINAL FALLBACK path (small ws): R9 kernels, unchanged.
// ---------------------------------------------------------------------------
__global__ __launch_bounds__(256) void gemm_in(
    const float* __restrict__ X, const float* __restrict__ W1,
    const float* __restrict__ b1, float* __restrict__ A)
{
    __shared__ unsigned short alds[8 * 64 * 8];
    __shared__ unsigned short blds[10 * 64 * 8];
    const int tid = threadIdx.x;
    const int w = tid >> 6, l = tid & 63, lg = l >> 4, ln = l & 15;
    const size_t m0 = (size_t)blockIdx.x * 128;
    const int n0 = blockIdx.y * 160;

    f32x4 acc[2][10];
    #pragma unroll
    for (int q = 0; q < 2; ++q)
        #pragma unroll
        for (int nt = 0; nt < 10; ++nt) acc[q][nt] = (f32x4){0.f,0.f,0.f,0.f};

    for (int kt = 0; kt < 10; ++kt) {
        const int kc = kt * 32;
        __syncthreads();
        #pragma unroll
        for (int rep = 0; rep < 2; ++rep) {
            int e = tid + rep * 256;
            int row = e >> 2, kh = e & 3;
            int k0 = kc + kh * 8;
            uint4 p = load8_cvt(X + (m0 + row) * 300 + k0, true, 300 - k0);
            *(uint4*)&alds[(((row >> 4) * 64) + kh * 16 + (row & 15)) * 8] = p;
        }
        #pragma unroll
        for (int rep = 0; rep < 3; ++rep) {
            int e = tid + rep * 256;
            if (e < 640) {
                int nn = e >> 2, kh = e & 3;
                int n = n0 + nn;
                int k0 = kc + kh * 8;
                uint4 p = load8_cvt(W1 + (size_t)n * 600 + k0, n < 300, 300 - k0);
                *(uint4*)&blds[(((nn >> 4) * 64) + kh * 16 + (nn & 15)) * 8] = p;
            }
        }
        __syncthreads();
        bf16x8 bfr[10];
        #pragma unroll
        for (int nt = 0; nt < 10; ++nt) bfr[nt] = *(const bf16x8*)&blds[(nt * 64 + l) * 8];
        #pragma unroll
        for (int q = 0; q < 2; ++q) {
            bf16x8 afr = *(const bf16x8*)&alds[((w * 2 + q) * 64 + l) * 8];
            #pragma unroll
            for (int nt = 0; nt < 10; ++nt)
                acc[q][nt] = __builtin_amdgcn_mfma_f32_16x16x32_bf16(afr, bfr[nt], acc[q][nt], 0, 0, 0);
        }
    }

    #pragma unroll
    for (int q = 0; q < 2; ++q)
        #pragma unroll
        for (int nt = 0; nt < 10; ++nt) {
            int n = n0 + nt * 16 + ln;
            if (n < 300) {
                float bias = b1[n];
                size_t mr = m0 + (w * 2 + q) * 16 + lg * 4;
                #pragma unroll
                for (int i = 0; i < 4; ++i)
                    A[(mr + i) * 300 + n] = (acc[q][nt][i] + bias) * NL2E;
            }
        }
}

#define K2_STEP(P, tval, ASLOT, APTR, HPME, HPOTHER)                            \
    {                                                                           \
        const int t = (tval);                                                   \
        const int tt = t - 1;                                                   \
        const size_t so = (size_t)(tt >> 6) * 76800 + (size_t)(tt & 63) * 600;  \
        bf16x8 bfr[10];                                                         \
        _Pragma("unroll")                                                       \
        for (int kt = 0; kt < 10; ++kt)                                         \
            bfr[kt] = *(const bf16x8*)&hlds[P][(kt * 64 + l) * 8];              \
        f32x4 acc[3], accB[3];                                                  \
        _Pragma("unroll")                                                       \
        for (int q = 0; q < 3; ++q) {                                           \
            acc[q] = QOK(q) ? ASLOT[q] : (f32x4){0.f,0.f,0.f,0.f};              \
            accB[q] = (f32x4){0.f,0.f,0.f,0.f};                                 \
        }                                                                       \
        _Pragma("unroll")                                                       \
        for (int q = 0; q < 3; ++q)                                             \
            if (QOK(q)) ASLOT[q] = *(const f32x4*)(APTR + rq[q] * 4);           \
        APTR += 2400;                                                           \
        __builtin_amdgcn_s_setprio(1);                                          \
        _Pragma("unroll")                                                       \
        for (int kt = 0; kt < 5; ++kt) {                                        \
            acc[0]  = __builtin_amdgcn_mfma_f32_16x16x32_bf16(afrag[0][kt],   bfr[kt],   acc[0],  0, 0, 0); \
            accB[0] = __builtin_amdgcn_mfma_f32_16x16x32_bf16(afrag[0][kt+5], bfr[kt+5], accB[0], 0, 0, 0); \
            acc[1]  = __builtin_amdgcn_mfma_f32_16x16x32_bf16(afrag[1][kt],   bfr[kt],   acc[1],  0, 0, 0); \
            accB[1] = __builtin_amdgcn_mfma_f32_16x16x32_bf16(afrag[1][kt+5], bfr[kt+5], accB[1], 0, 0, 0); \
            if (w4) {                                                           \
                acc[2]  = __builtin_amdgcn_mfma_f32_16x16x32_bf16(afrag[2][kt],   bfr[kt],   acc[2],  0, 0, 0); \
                accB[2] = __builtin_amdgcn_mfma_f32_16x16x32_bf16(afrag[2][kt+5], bfr[kt+5], accB[2], 0, 0, 0); \
            }                                                                   \
        }                                                                       \
        __builtin_amdgcn_s_setprio(0);                                          \
        _Pragma("unroll")                                                       \
        for (int q = 0; q < 3; ++q) {                                           \
            if (!QOK(q)) continue;                                              \
            f32x4 hv;                                                           \
            _Pragma("unroll")                                                   \
            for (int i = 0; i < 4; ++i) {                                       \
                float zn = acc[q][i] + accB[q][i];                              \
                float ex, sg;                                                   \
                asm("v_exp_f32 %0, %1" : "=v"(ex) : "v"(zn));                   \
                asm("v_rcp_f32 %0, %1" : "=v"(sg) : "v"(1.0f + ex));            \
                hv[i] = sg;                                                     \
            }                                                                   \
            unsigned plo, phi;                                                  \
            asm("v_cvt_pk_bf16_f32 %0, %1, %2" : "=v"(plo) : "v"(hv[0]), "v"(hv[1])); \
            asm("v_cvt_pk_bf16_f32 %0, %1, %2" : "=v"(phi) : "v"(hv[2]), "v"(hv[3])); \
            HPME[q].x = plo; HPME[q].y = phi;                                   \
            *(uint2*)((char*)hlds + ((P) ^ 1) * 10240 + ldsoff[q]) = HPME[q];   \
            if (t > 0 && rq[q] < 300)                                           \
                *(uint2*)(sbase + so + rq[q] * 2) = HPOTHER[q];                 \
        }                                                                       \
        asm volatile("s_waitcnt lgkmcnt(0)" ::: "memory");                      \
        __builtin_amdgcn_s_barrier();                                           \
        asm volatile("" ::: "memory");                                          \
    }

__global__ __launch_bounds__(512) void elman_rec_mfma(
    const float* __restrict__ W1, float* __restrict__ buf,
    float* __restrict__ hfinal)
{
    __shared__ unsigned short hlds[2][10 * 64 * 8];
    const int tid = threadIdx.x;
    const int w = tid >> 6, l = tid & 63, lg = l >> 4, ln = l & 15;
    const bool w4 = (w < 4);
    const int bb = blockIdx.x * 16 + ln;

    int rq[3], ldsoff[3];
    #pragma unroll
    for (int q = 0; q < 3; ++q) {
        int tile = w4 ? (3 * w + q) : (12 + 2 * (w - 4) + q);
        int r = tile * 16 + 4 * lg;
        rq[q] = r;
        ldsoff[q] = (((r >> 5) * 64 + ((r >> 3) & 3) * 16 + ln) * 8 + (r & 7)) * 2;
    }

    bf16x8 afrag[3][10];
    #pragma unroll
    for (int q = 0; q < 3; ++q) {
        #pragma unroll
        for (int kt = 0; kt < 10; ++kt) {
            bool qa = (q < 2) || w4;
            int tile = w4 ? (3 * w + q) : (12 + 2 * (w - 4) + q);
            int r = tile * 16 + ln;
            int k0 = kt * 32 + lg * 8;
            uint4 p = load8_cvt_s(W1 + (size_t)r * 600 + 300 + k0,
                                  qa && r < 300, 300 - k0, NL2E);
            union { uint4 u; bf16x8 s; } cv; cv.u = p;
            afrag[q][kt] = cv.s;
        }
    }

    for (int i = tid; i < 10 * 64 * 8; i += 512) hlds[0][i] = 0;

    const char* abase = (const char*)(buf + (size_t)bb * T_ * 300);
    char* sbase = (char*)buf + (size_t)bb * 16 * 76800;

    f32x4 A0[3], A1[3];
    #pragma unroll
    for (int q = 0; q < 3; ++q)
        if (QOK(q)) {
            A0[q] = *(const f32x4*)(abase + rq[q] * 4);
            A1[q] = *(const f32x4*)(abase + 1200 + rq[q] * 4);
        }
    const char* aptr0 = abase + 2400;
    const char* aptr1 = abase + 3600;
    uint2 hpA[3], hpB[3];
    __syncthreads();

    for (int t2 = 0; t2 < T_; t2 += 2) {
        K2_STEP(0, t2,     A0, aptr0, hpA, hpB)
        K2_STEP(1, t2 + 1, A1, aptr1, hpB, hpA)
    }

    {
        const int tt = T_ - 1;
        const size_t so = (size_t)(tt >> 6) * 76800 + (size_t)(tt & 63) * 600;
        #pragma unroll
        for (int q = 0; q < 3; ++q)
            if (QOK(q) && rq[q] < 300) {
                *(uint2*)(sbase + so + rq[q] * 2) = hpB[q];
                f32x4 hv;
                union { float f; unsigned u; } c0, c1, c2, c3;
                c0.u = hpB[q].x << 16; c1.u = hpB[q].x & 0xFFFF0000u;
                c2.u = hpB[q].y << 16; c3.u = hpB[q].y & 0xFFFF0000u;
                hv[0] = c0.f; hv[1] = c1.f; hv[2] = c2.f; hv[3] = c3.f;
                *(f32x4*)(hfinal + bb * 300 + rq[q]) = hv;
            }
    }
}

__global__ __launch_bounds__(256) void gemm_out(
    float* __restrict__ buf, const float* __restrict__ W2,
    const float* __restrict__ b2)
{
    __shared__ unsigned short alds[4 * 64 * 8];
    __shared__ unsigned short blds[19 * 64 * 8];
    const int tid = threadIdx.x;
    const int w = tid >> 6, l = tid & 63, lg = l >> 4, ln = l & 15;
    const size_t chunk = blockIdx.x;
    const char* pbase = (const char*)buf + chunk * 76800;

    f32x4 acc[19];
    #pragma unroll
    for (int nt = 0; nt < 19; ++nt) acc[nt] = (f32x4){0.f,0.f,0.f,0.f};

    for (int kt = 0; kt < 10; ++kt) {
        const int kc = kt * 32;
        __syncthreads();
        {
            int row = tid >> 2, kh = tid & 3;
            int k0 = kc + kh * 8;
            const char* p = pbase + row * 600;
            uint2 lo = make_uint2(0u, 0u), hi = make_uint2(0u, 0u);
            int krem = 300 - k0;
            if (krem >= 8)      { lo = *(const uint2*)(p + k0 * 2); hi = *(const uint2*)(p + k0 * 2 + 8); }
            else if (krem >= 4) { lo = *(const uint2*)(p + k0 * 2); }
            uint4 pk; pk.x = lo.x; pk.y = lo.y; pk.z = hi.x; pk.w = hi.y;
            *(uint4*)&alds[(((row >> 4) * 64) + kh * 16 + (row & 15)) * 8] = pk;
        }
        #pragma unroll
        for (int rep = 0; rep < 5; ++rep) {
            int e = tid + rep * 256;
            if (e < 1216) {
                int nn = e >> 2, kh = e & 3;
                int k0 = kc + kh * 8;
                uint4 p = load8_cvt(W2 + (size_t)nn * 300 + k0, nn < 300, 300 - k0);
                *(uint4*)&blds[(((nn >> 4) * 64) + kh * 16 + (nn & 15)) * 8] = p;
            }
        }
        __syncthreads();
        bf16x8 afr = *(const bf16x8*)&alds[(w * 64 + l) * 8];
        #pragma unroll
        for (int nt = 0; nt < 19; ++nt) {
            bf16x8 bfr = *(const bf16x8*)&blds[(nt * 64 + l) * 8];
            acc[nt] = __builtin_amdgcn_mfma_f32_16x16x32_bf16(afr, bfr, acc[nt], 0, 0, 0);
        }
    }

    float* frow = buf + chunk * 19200;
    #pragma unroll
    for (int nt = 0; nt < 19; ++nt) {
        int n = nt * 16 + ln;
        if (n < 300) {
            float bias = b2[n];
            int mr = w * 16 + lg * 4;
            #pragma unroll
            for (int i = 0; i < 4; ++i)
                frow[(mr + i) * 300 + n] = acc[nt][i] + bias;
        }
    }
}

// ---------------------------------------------------------------------------
extern "C" void kernel_launch(void* const* d_in, const int* in_sizes, int n_in,
                              void* d_out, int out_size, void* d_ws, size_t ws_size,
                              hipStream_t stream)
{
    const float* x  = (const float*)d_in[0];
    const float* W1 = (const float*)d_in[1];
    const float* b1 = (const float*)d_in[2];
    const float* W2 = (const float*)d_in[3];
    const float* b2 = (const float*)d_in[4];

    float* out    = (float*)d_out;
    float* hfinal = out + (size_t)HB;

    if (ws_size >= WOFF + 2 * WSZ1) {
        // full path: pre-converted W + time-major h in ws
        char* ws  = (char*)d_ws;
        char* wbf = ws + WOFF;
        convert_w<<<20, 256, 0, stream>>>(W1, W2, wbf);
        gemm_in_t2b<<<512, 512, 0, stream>>>(x, wbf, b1, ws);
        elman_rec_ws<<<8, 512, 0, stream>>>(W1, hfinal, ws);
        gemm_out_t2b<<<512, 512, 0, stream>>>(ws, wbf + WSZ1, b2, out);
    } else if (ws_size >= HT4 + 2 * 76800) {
        // middle path: time-major h in ws, inline W conversion
        gemm_in_t2<<<512, 512, 0, stream>>>(x, W1, b1, (char*)d_ws);
        elman_rec_ws<<<8, 512, 0, stream>>>(W1, hfinal, (char*)d_ws);
        gemm_out_t2<<<512, 512, 0, stream>>>((const char*)d_ws, W2, b2, out);
    } else {
        // fallback: everything in d_out
        gemm_in<<<dim3(1024, 2), 256, 0, stream>>>(x, W1, b1, out);
        elman_rec_mfma<<<8, 512, 0, stream>>>(W1, out, hfinal);
        gemm_out<<<2048, 256, 0, stream>>>(out, W2, b2);
    }
}

// Round 19
// 978.551 us; speedup vs baseline: 1.3229x; 1.0005x over previous
//
#include <hip/hip_runtime.h>

typedef __attribute__((ext_vector_type(4))) float f32x4;
typedef __attribute__((ext_vector_type(8))) short bf16x8;

#define B_   128
#define T_   1024
#define NROW 131072      // B*T
#define HB   (NROW*300)  // floats in the [B*T][300] matrix
#define NL2E -1.44269504088896340736f   // -log2(e)

#define HT4   ((size_t)T_ * 75 * 128 * 8)          // 78,643,200 B (h_T4)
#define WOFF  (HT4 + 2 * 76800)                    // prefetch-overrun slack end
#define WSZ1  194560                               // 10 kt * 19456 B per W

__device__ inline unsigned short f2bf(float f) {
    union { float f; unsigned int u; } v; v.f = f;
    unsigned int r = v.u + 0x7FFFu + ((v.u >> 16) & 1u);
    return (unsigned short)(r >> 16);
}

__device__ inline uint4 load8_cvt_s(const float* src, bool rowok, int krem, float scale) {
    f32x4 v0 = {0.f,0.f,0.f,0.f}, v1 = {0.f,0.f,0.f,0.f};
    if (rowok) {
        if (krem >= 8)      { v0 = *(const f32x4*)src; v1 = *(const f32x4*)(src + 4); }
        else if (krem >= 4) { v0 = *(const f32x4*)src; }
    }
    v0 *= scale; v1 *= scale;
    uint4 p;
    p.x = (unsigned)f2bf(v0[0]) | ((unsigned)f2bf(v0[1]) << 16);
    p.y = (unsigned)f2bf(v0[2]) | ((unsigned)f2bf(v0[3]) << 16);
    p.z = (unsigned)f2bf(v1[0]) | ((unsigned)f2bf(v1[1]) << 16);
    p.w = (unsigned)f2bf(v1[2]) | ((unsigned)f2bf(v1[3]) << 16);
    return p;
}

__device__ inline uint4 load8_cvt(const float* src, bool rowok, int krem) {
    return load8_cvt_s(src, rowok, krem, 1.0f);
}

// ---------------------------------------------------------------------------
// K0: one-time W conversion into frag-linear bf16 in ws tail.
// blocks 0-9: W1x (NL2E-scaled); blocks 10-19: W2.
// ---------------------------------------------------------------------------
__global__ __launch_bounds__(256) void convert_w(
    const float* __restrict__ W1, const float* __restrict__ W2,
    char* __restrict__ wsbase)
{
    const int kt = blockIdx.x % 10;
    const bool isW2 = blockIdx.x >= 10;
    char* dst = wsbase + (isW2 ? WSZ1 : 0) + (size_t)kt * 19456;
    #pragma unroll
    for (int rep = 0; rep < 5; ++rep) {
        int e = threadIdx.x + rep * 256;
        if (e < 1216) {
            int nn = e >> 2, kh = e & 3, k0 = kt * 32 + kh * 8;
            uint4 p = isW2
                ? load8_cvt(W2 + (size_t)nn * 300 + k0, nn < 300, 300 - k0)
                : load8_cvt_s(W1 + (size_t)nn * 600 + k0, nn < 300, 300 - k0, NL2E);
            int perm = ((nn >> 4) * 64) + (kh * 16) + (nn & 15);
            *(uint4*)(dst + (size_t)perm * 16) = p;
        }
    }
}

// ---------------------------------------------------------------------------
// K1-T2b (ws path): A'_T4[t][rg][b][4 bf16] time-major into ws; 2 t/block.
// W1x tile staged as a plain linear uint4 copy from pre-converted bf16.
// ---------------------------------------------------------------------------
__global__ __launch_bounds__(512) void gemm_in_t2b(
    const float* __restrict__ X, const char* __restrict__ wbf1,
    const float* __restrict__ b1, char* __restrict__ aws)
{
    __shared__ unsigned short wlds[19 * 64 * 8];
    __shared__ unsigned short xlds[2][8 * 64 * 8];
    const int tid = threadIdx.x;
    const int w = tid >> 6, l = tid & 63, lg = l >> 4, ln = l & 15;
    const int th = w >> 2, wb = w & 3;
    const int t = blockIdx.x * 2 + th;

    f32x4 acc[2][19];
    #pragma unroll
    for (int q = 0; q < 2; ++q)
        #pragma unroll
        for (int mt = 0; mt < 19; ++mt) acc[q][mt] = (f32x4){0.f,0.f,0.f,0.f};

    for (int kt = 0; kt < 10; ++kt) {
        const int kc = kt * 32;
        __syncthreads();
        // stage W1x tile: linear bf16 copy (no cvt VALU)
        {
            const uint4* wsrc = (const uint4*)(wbf1 + (size_t)kt * 19456);
            #pragma unroll
            for (int rep = 0; rep < 3; ++rep) {
                int e = tid + rep * 512;
                if (e < 1216) *(uint4*)&wlds[e * 8] = wsrc[e];
            }
        }
        // stage x tiles for both t (needs cvt)
        #pragma unroll
        for (int tt = 0; tt < 2; ++tt) {
            int e = tid;
            int row = e >> 2, kh = e & 3;
            int k0 = kc + kh * 8;
            uint4 p = load8_cvt(X + ((size_t)row * 1024 + blockIdx.x * 2 + tt) * 300 + k0,
                                true, 300 - k0);
            *(uint4*)&xlds[tt][(((row >> 4) * 64) + kh * 16 + (row & 15)) * 8] = p;
        }
        __syncthreads();
        bf16x8 wfr[19];
        #pragma unroll
        for (int mt = 0; mt < 19; ++mt) wfr[mt] = *(const bf16x8*)&wlds[(mt * 64 + l) * 8];
        #pragma unroll
        for (int q = 0; q < 2; ++q) {
            bf16x8 xfr = *(const bf16x8*)&xlds[th][((wb * 2 + q) * 64 + l) * 8];
            #pragma unroll
            for (int mt = 0; mt < 19; ++mt)
                acc[q][mt] = __builtin_amdgcn_mfma_f32_16x16x32_bf16(wfr[mt], xfr, acc[q][mt], 0, 0, 0);
        }
    }

    char* tb = aws + (size_t)t * 76800;
    #pragma unroll
    for (int q = 0; q < 2; ++q) {
        int b = (wb * 2 + q) * 16 + ln;
        #pragma unroll
        for (int mt = 0; mt < 19; ++mt) {
            int rg = mt * 4 + lg;
            if (rg < 75) {
                f32x4 bias = *(const f32x4*)(b1 + mt * 16 + lg * 4);
                float v0 = acc[q][mt][0] + bias[0] * NL2E;
                float v1 = acc[q][mt][1] + bias[1] * NL2E;
                float v2 = acc[q][mt][2] + bias[2] * NL2E;
                float v3 = acc[q][mt][3] + bias[3] * NL2E;
                unsigned plo, phi;
                asm("v_cvt_pk_bf16_f32 %0, %1, %2" : "=v"(plo) : "v"(v0), "v"(v1));
                asm("v_cvt_pk_bf16_f32 %0, %1, %2" : "=v"(phi) : "v"(v2), "v"(v3));
                uint2 pk; pk.x = plo; pk.y = phi;
                *(uint2*)(tb + (size_t)rg * 1024 + b * 8) = pk;
            }
        }
    }
}

#define QOK(q) ((q) < 2 || w4)

// ---------------------------------------------------------------------------
// K2-WS3 (best known): recurrence; A'/h in ws time-major (h(t) overwrites
// A'(t) in place; race-free). 8 blocks x 512 thr. Per-q MFMA/sigmoid
// interleave; uniform time pointer + constant lane offsets; exp2 sigmoid;
// one lgkmcnt(0)+s_barrier per step.
// ---------------------------------------------------------------------------
#define K2_CHAIN(q)                                                             \
    _Pragma("unroll")                                                           \
    for (int kt = 0; kt < 5; ++kt) {                                            \
        acc[q]  = __builtin_amdgcn_mfma_f32_16x16x32_bf16(afrag[q][kt],   bfr[kt],   acc[q],  0, 0, 0); \
        accB[q] = __builtin_amdgcn_mfma_f32_16x16x32_bf16(afrag[q][kt+5], bfr[kt+5], accB[q], 0, 0, 0); \
    }

#define K2_SIG(q, P, HWT, t)                                                    \
    {                                                                           \
        f32x4 hv;                                                               \
        _Pragma("unroll")                                                       \
        for (int i = 0; i < 4; ++i) {                                           \
            float zn = acc[q][i] + accB[q][i];      /* = -z*log2e */            \
            float ex, sg;                                                       \
            asm("v_exp_f32 %0, %1" : "=v"(ex) : "v"(zn));                       \
            asm("v_rcp_f32 %0, %1" : "=v"(sg) : "v"(1.0f + ex));                \
            hv[i] = sg;                                                         \
        }                                                                       \
        unsigned plo, phi;                                                      \
        asm("v_cvt_pk_bf16_f32 %0, %1, %2" : "=v"(plo) : "v"(hv[0]), "v"(hv[1])); \
        asm("v_cvt_pk_bf16_f32 %0, %1, %2" : "=v"(phi) : "v"(hv[2]), "v"(hv[3])); \
        uint2 pk; pk.x = plo; pk.y = phi;                                       \
        *(uint2*)((char*)hlds + ((P) ^ 1) * 10240 + ldsoff[q]) = pk;            \
        if (rq[q] < 300) {                                                      \
            *(uint2*)((HWT) + loff[q]) = pk;    /* h(t) overwrites A'(t) */     \
            if ((t) == T_ - 1)                                                  \
                *(f32x4*)(hfinal + bb * 300 + rq[q]) = hv;                      \
        }                                                                       \
    }

#define K2W_STEP(P, tval, AS, HWT)                                              \
    {                                                                           \
        const int t = (tval);                                                   \
        bf16x8 bfr[10];                                                         \
        _Pragma("unroll")                                                       \
        for (int kt = 0; kt < 10; ++kt)                                         \
            bfr[kt] = *(const bf16x8*)&hlds[P][(kt * 64 + l) * 8];              \
        f32x4 acc[3], accB[3];                                                  \
        _Pragma("unroll")                                                       \
        for (int q = 0; q < 3; ++q) {                                           \
            union { float f; unsigned u; } u0, u1, u2, u3;                      \
            u0.u = AS[q].x << 16; u1.u = AS[q].x & 0xFFFF0000u;                 \
            u2.u = AS[q].y << 16; u3.u = AS[q].y & 0xFFFF0000u;                 \
            acc[q] = (f32x4){u0.f, u1.f, u2.f, u3.f};                           \
            accB[q] = (f32x4){0.f,0.f,0.f,0.f};                                 \
        }                                                                       \
        /* prefetch A'(t+2): uniform base + const lane offset */                \
        _Pragma("unroll")                                                       \
        for (int q = 0; q < 3; ++q)                                             \
            if (QOK(q)) AS[q] = *(const uint2*)((HWT) + 153600 + loff[q]);      \
        __builtin_amdgcn_s_setprio(1);                                          \
        K2_CHAIN(0)                                                             \
        K2_CHAIN(1)                                                             \
        __builtin_amdgcn_s_setprio(0);                                          \
        K2_SIG(0, P, HWT, t)                                                    \
        if (w4) {                                                               \
            __builtin_amdgcn_s_setprio(1);                                      \
            K2_CHAIN(2)                                                         \
            __builtin_amdgcn_s_setprio(0);                                      \
        }                                                                       \
        K2_SIG(1, P, HWT, t)                                                    \
        if (w4) K2_SIG(2, P, HWT, t)                                            \
        HWT += 153600;                                                          \
        asm volatile("s_waitcnt lgkmcnt(0)" ::: "memory");                      \
        __builtin_amdgcn_s_barrier();                                           \
        asm volatile("" ::: "memory");                                          \
    }

__global__ __launch_bounds__(512) void elman_rec_ws(
    const float* __restrict__ W1, float* __restrict__ hfinal,
    char* __restrict__ hws)
{
    __shared__ unsigned short hlds[2][10 * 64 * 8];   // 2 x 10240 B
    const int tid = threadIdx.x;
    const int w = tid >> 6, l = tid & 63, lg = l >> 4, ln = l & 15;
    const bool w4 = (w < 4);
    const int bb = blockIdx.x * 16 + ln;    // this lane's batch (B/C column)

    int rq[3], ldsoff[3], loff[3];
    #pragma unroll
    for (int q = 0; q < 3; ++q) {
        int tile = w4 ? (3 * w + q) : (12 + 2 * (w - 4) + q);
        int r = tile * 16 + 4 * lg;
        rq[q] = r;
        ldsoff[q] = (((r >> 5) * 64 + ((r >> 3) & 3) * 16 + ln) * 8 + (r & 7)) * 2;
        int rgc = r >> 2; if (rgc > 74) rgc = 74;
        loff[q] = rgc * 1024 + bb * 8;      // constant per-lane ws offset
    }

    // W1h A-fragments, scaled by -log2e (rows >=300, k>=300 zeroed)
    bf16x8 afrag[3][10];
    #pragma unroll
    for (int q = 0; q < 3; ++q) {
        #pragma unroll
        for (int kt = 0; kt < 10; ++kt) {
            bool qa = (q < 2) || w4;
            int tile = w4 ? (3 * w + q) : (12 + 2 * (w - 4) + q);
            int r = tile * 16 + ln;
            int k0 = kt * 32 + lg * 8;
            uint4 p = load8_cvt_s(W1 + (size_t)r * 600 + 300 + k0,
                                  qa && r < 300, 300 - k0, NL2E);
            union { uint4 u; bf16x8 s; } cv; cv.u = p;
            afrag[q][kt] = cv.s;
        }
    }

    for (int i = tid; i < 10 * 64 * 8; i += 512) hlds[0][i] = 0;

    // uniform time pointers (per parity), advanced 2 steps per pair
    char* HWT0 = hws;            // even steps t = 0,2,...
    char* HWT1 = hws + 76800;    // odd steps  t = 1,3,...

    uint2 AS0[3], AS1[3];
    #pragma unroll
    for (int q = 0; q < 3; ++q)
        if (QOK(q)) {
            AS0[q] = *(const uint2*)(HWT0 + loff[q]);   // A'(0)
            AS1[q] = *(const uint2*)(HWT1 + loff[q]);   // A'(1)
        }
    __syncthreads();

    for (int t2 = 0; t2 < T_; t2 += 2) {
        K2W_STEP(0, t2,     AS0, HWT0)
        K2W_STEP(1, t2 + 1, AS1, HWT1)
    }
}

// ---------------------------------------------------------------------------
// K3-T2b: out[b][t][n] = sum_r h_T4[t][r][b]*W2[n][r] + b2[n]; 2 t/block.
// W2 tile staged as a plain linear uint4 copy from pre-converted bf16.
// ---------------------------------------------------------------------------
__global__ __launch_bounds__(512) void gemm_out_t2b(
    const char* __restrict__ hws, const char* __restrict__ wbf2,
    const float* __restrict__ b2, float* __restrict__ out)
{
    __shared__ unsigned short ahs[2][8 * 132 * 4];
    __shared__ unsigned short blds[19 * 64 * 8];
    const int tid = threadIdx.x;
    const int w = tid >> 6, l = tid & 63, lg = l >> 4, ln = l & 15;
    const int th = w >> 2, wb = w & 3;
    const int t = blockIdx.x * 2 + th;

    f32x4 acc[2][19];
    #pragma unroll
    for (int q = 0; q < 2; ++q)
        #pragma unroll
        for (int nt = 0; nt < 19; ++nt) acc[q][nt] = (f32x4){0.f,0.f,0.f,0.f};

    for (int kt = 0; kt < 10; ++kt) {
        __syncthreads();
        #pragma unroll
        for (int tt = 0; tt < 2; ++tt) {
            const char* hbase = hws + (size_t)(blockIdx.x * 2 + tt) * 76800;
            #pragma unroll
            for (int it = 0; it < 2; ++it) {
                int e = tid + it * 512;
                int rg = e >> 7, b = e & 127;
                int rgg = kt * 8 + rg;
                uint2 v = make_uint2(0u, 0u);
                if (rgg < 75) v = *(const uint2*)(hbase + (size_t)rgg * 1024 + b * 8);
                *(uint2*)&ahs[tt][(rg * 132 + b) * 4] = v;
            }
        }
        // stage W2 tile: linear bf16 copy
        {
            const uint4* wsrc = (const uint4*)(wbf2 + (size_t)kt * 19456);
            #pragma unroll
            for (int rep = 0; rep < 3; ++rep) {
                int e = tid + rep * 512;
                if (e < 1216) *(uint4*)&blds[e * 8] = wsrc[e];
            }
        }
        __syncthreads();
        bf16x8 bfr[19];
        #pragma unroll
        for (int nt = 0; nt < 19; ++nt) bfr[nt] = *(const bf16x8*)&blds[(nt * 64 + l) * 8];
        #pragma unroll
        for (int q = 0; q < 2; ++q) {
            int b = (wb * 2 + q) * 16 + ln;
            uint2 u0 = *(const uint2*)&ahs[th][((2 * lg)     * 132 + b) * 4];
            uint2 u1 = *(const uint2*)&ahs[th][((2 * lg + 1) * 132 + b) * 4];
            union { uint4 u; bf16x8 s; } cv;
            cv.u.x = u0.x; cv.u.y = u0.y; cv.u.z = u1.x; cv.u.w = u1.y;
            bf16x8 afr = cv.s;
            #pragma unroll
            for (int nt = 0; nt < 19; ++nt)
                acc[q][nt] = __builtin_amdgcn_mfma_f32_16x16x32_bf16(afr, bfr[nt], acc[q][nt], 0, 0, 0);
        }
    }

    #pragma unroll
    for (int q = 0; q < 2; ++q)
        #pragma unroll
        for (int nt = 0; nt < 19; ++nt) {
            int n = nt * 16 + ln;
            if (n < 300) {
                float bias = b2[n];
                int b0r = (wb * 2 + q) * 16 + lg * 4;
                #pragma unroll
                for (int i = 0; i < 4; ++i)
                    out[((size_t)(b0r + i) * T_ + t) * 300 + n] = acc[q][nt][i] + bias;
            }
        }
}

// ---------------------------------------------------------------------------
// MIDDLE PATH (ws fits h but not W): inline W conversion.
// ---------------------------------------------------------------------------
__global__ __launch_bounds__(512) void gemm_in_t2(
    const float* __restrict__ X, const float* __restrict__ W1,
    const float* __restrict__ b1, char* __restrict__ aws)
{
    __shared__ unsigned short wlds[19 * 64 * 8];
    __shared__ unsigned short xlds[2][8 * 64 * 8];
    const int tid = threadIdx.x;
    const int w = tid >> 6, l = tid & 63, lg = l >> 4, ln = l & 15;
    const int th = w >> 2, wb = w & 3;
    const int t = blockIdx.x * 2 + th;

    f32x4 acc[2][19];
    #pragma unroll
    for (int q = 0; q < 2; ++q)
        #pragma unroll
        for (int mt = 0; mt < 19; ++mt) acc[q][mt] = (f32x4){0.f,0.f,0.f,0.f};

    for (int kt = 0; kt < 10; ++kt) {
        const int kc = kt * 32;
        __syncthreads();
        #pragma unroll
        for (int rep = 0; rep < 3; ++rep) {
            int e = tid + rep * 512;
            if (e < 1216) {
                int nn = e >> 2, kh = e & 3;
                int k0 = kc + kh * 8;
                uint4 p = load8_cvt_s(W1 + (size_t)nn * 600 + k0, nn < 300, 300 - k0, NL2E);
                *(uint4*)&wlds[(((nn >> 4) * 64) + kh * 16 + (nn & 15)) * 8] = p;
            }
        }
        #pragma unroll
        for (int tt = 0; tt < 2; ++tt) {
            int e = tid;
            int row = e >> 2, kh = e & 3;
            int k0 = kc + kh * 8;
            uint4 p = load8_cvt(X + ((size_t)row * 1024 + blockIdx.x * 2 + tt) * 300 + k0,
                                true, 300 - k0);
            *(uint4*)&xlds[tt][(((row >> 4) * 64) + kh * 16 + (row & 15)) * 8] = p;
        }
        __syncthreads();
        bf16x8 wfr[19];
        #pragma unroll
        for (int mt = 0; mt < 19; ++mt) wfr[mt] = *(const bf16x8*)&wlds[(mt * 64 + l) * 8];
        #pragma unroll
        for (int q = 0; q < 2; ++q) {
            bf16x8 xfr = *(const bf16x8*)&xlds[th][((wb * 2 + q) * 64 + l) * 8];
            #pragma unroll
            for (int mt = 0; mt < 19; ++mt)
                acc[q][mt] = __builtin_amdgcn_mfma_f32_16x16x32_bf16(wfr[mt], xfr, acc[q][mt], 0, 0, 0);
        }
    }

    char* tb = aws + (size_t)t * 76800;
    #pragma unroll
    for (int q = 0; q < 2; ++q) {
        int b = (wb * 2 + q) * 16 + ln;
        #pragma unroll
        for (int mt = 0; mt < 19; ++mt) {
            int rg = mt * 4 + lg;
            if (rg < 75) {
                f32x4 bias = *(const f32x4*)(b1 + mt * 16 + lg * 4);
                float v0 = acc[q][mt][0] + bias[0] * NL2E;
                float v1 = acc[q][mt][1] + bias[1] * NL2E;
                float v2 = acc[q][mt][2] + bias[2] * NL2E;
                float v3 = acc[q][mt][3] + bias[3] * NL2E;
                unsigned plo, phi;
                asm("v_cvt_pk_bf16_f32 %0, %1, %2" : "=v"(plo) : "v"(v0), "v"(v1));
                asm("v_cvt_pk_bf16_f32 %0, %1, %2" : "=v"(phi) : "v"(v2), "v"(v3));
                uint2 pk; pk.x = plo; pk.y = phi;
                *(uint2*)(tb + (size_t)rg * 1024 + b * 8) = pk;
            }
        }
    }
}

__global__ __launch_bounds__(512) void gemm_out_t2(
    const char* __restrict__ hws, const float* __restrict__ W2,
    const float* __restrict__ b2, float* __restrict__ out)
{
    __shared__ unsigned short ahs[2][8 * 132 * 4];
    __shared__ unsigned short blds[19 * 64 * 8];
    const int tid = threadIdx.x;
    const int w = tid >> 6, l = tid & 63, lg = l >> 4, ln = l & 15;
    const int th = w >> 2, wb = w & 3;
    const int t = blockIdx.x * 2 + th;

    f32x4 acc[2][19];
    #pragma unroll
    for (int q = 0; q < 2; ++q)
        #pragma unroll
        for (int nt = 0; nt < 19; ++nt) acc[q][nt] = (f32x4){0.f,0.f,0.f,0.f};

    for (int kt = 0; kt < 10; ++kt) {
        const int kc = kt * 32;
        __syncthreads();
        #pragma unroll
        for (int tt = 0; tt < 2; ++tt) {
            const char* hbase = hws + (size_t)(blockIdx.x * 2 + tt) * 76800;
            #pragma unroll
            for (int it = 0; it < 2; ++it) {
                int e = tid + it * 512;
                int rg = e >> 7, b = e & 127;
                int rgg = kt * 8 + rg;
                uint2 v = make_uint2(0u, 0u);
                if (rgg < 75) v = *(const uint2*)(hbase + (size_t)rgg * 1024 + b * 8);
                *(uint2*)&ahs[tt][(rg * 132 + b) * 4] = v;
            }
        }
        #pragma unroll
        for (int rep = 0; rep < 3; ++rep) {
            int e = tid + rep * 512;
            if (e < 1216) {
                int nn = e >> 2, kh = e & 3;
                int k0 = kc + kh * 8;
                uint4 p = load8_cvt(W2 + (size_t)nn * 300 + k0, nn < 300, 300 - k0);
                *(uint4*)&blds[(((nn >> 4) * 64) + kh * 16 + (nn & 15)) * 8] = p;
            }
        }
        __syncthreads();
        bf16x8 bfr[19];
        #pragma unroll
        for (int nt = 0; nt < 19; ++nt) bfr[nt] = *(const bf16x8*)&blds[(nt * 64 + l) * 8];
        #pragma unroll
        for (int q = 0; q < 2; ++q) {
            int b = (wb * 2 + q) * 16 + ln;
            uint2 u0 = *(const uint2*)&ahs[th][((2 * lg)     * 132 + b) * 4];
            uint2 u1 = *(const uint2*)&ahs[th][((2 * lg + 1) * 132 + b) * 4];
            union { uint4 u; bf16x8 s; } cv;
            cv.u.x = u0.x; cv.u.y = u0.y; cv.u.z = u1.x; cv.u.w = u1.y;
            bf16x8 afr = cv.s;
            #pragma unroll
            for (int nt = 0; nt < 19; ++nt)
                acc[q][nt] = __builtin_amdgcn_mfma_f32_16x16x32_bf16(afr, bfr[nt], acc[q][nt], 0, 0, 0);
        }
    }

    #pragma unroll
    for (int q = 0; q < 2; ++q)
        #pragma unroll
        for (int nt = 0; nt < 19; ++nt) {
            int n = nt * 16 + ln;
            if (n < 300) {
                float bias = b2[n];
                int b0r = (wb * 2 + q) * 16 + lg * 4;
                #pragma unroll
                for (int i = 0; i < 4; ++i)
                    out[((size_t)(b0r + i) * T_ + t) * 300 + n] = acc[q][nt][i] + bias;
            }
        }
}

// ---------------------------------------------------------------------------
// FINAL FALLBACK path (small ws): R9 kernels, unchanged.
// ---------------------------------------------------------------------------
__global__ __launch_bounds__(256) void gemm_in(
    const float* __restrict__ X, const float* __restrict__ W1,
    const float* __restrict__ b1, float* __restrict__ A)
{
    __shared__ unsigned short alds[8 * 64 * 8];
    __shared__ unsigned short blds[10 * 64 * 8];
    const int tid = threadIdx.x;
    const int w = tid >> 6, l = tid & 63, lg = l >> 4, ln = l & 15;
    const size_t m0 = (size_t)blockIdx.x * 128;
    const int n0 = blockIdx.y * 160;

    f32x4 acc[2][10];
    #pragma unroll
    for (int q = 0; q < 2; ++q)
        #pragma unroll
        for (int nt = 0; nt < 10; ++nt) acc[q][nt] = (f32x4){0.f,0.f,0.f,0.f};

    for (int kt = 0; kt < 10; ++kt) {
        const int kc = kt * 32;
        __syncthreads();
        #pragma unroll
        for (int rep = 0; rep < 2; ++rep) {
            int e = tid + rep * 256;
            int row = e >> 2, kh = e & 3;
            int k0 = kc + kh * 8;
            uint4 p = load8_cvt(X + (m0 + row) * 300 + k0, true, 300 - k0);
            *(uint4*)&alds[(((row >> 4) * 64) + kh * 16 + (row & 15)) * 8] = p;
        }
        #pragma unroll
        for (int rep = 0; rep < 3; ++rep) {
            int e = tid + rep * 256;
            if (e < 640) {
                int nn = e >> 2, kh = e & 3;
                int n = n0 + nn;
                int k0 = kc + kh * 8;
                uint4 p = load8_cvt(W1 + (size_t)n * 600 + k0, n < 300, 300 - k0);
                *(uint4*)&blds[(((nn >> 4) * 64) + kh * 16 + (nn & 15)) * 8] = p;
            }
        }
        __syncthreads();
        bf16x8 bfr[10];
        #pragma unroll
        for (int nt = 0; nt < 10; ++nt) bfr[nt] = *(const bf16x8*)&blds[(nt * 64 + l) * 8];
        #pragma unroll
        for (int q = 0; q < 2; ++q) {
            bf16x8 afr = *(const bf16x8*)&alds[((w * 2 + q) * 64 + l) * 8];
            #pragma unroll
            for (int nt = 0; nt < 10; ++nt)
                acc[q][nt] = __builtin_amdgcn_mfma_f32_16x16x32_bf16(afr, bfr[nt], acc[q][nt], 0, 0, 0);
        }
    }

    #pragma unroll
    for (int q = 0; q < 2; ++q)
        #pragma unroll
        for (int nt = 0; nt < 10; ++nt) {
            int n = n0 + nt * 16 + ln;
            if (n < 300) {
                float bias = b1[n];
                size_t mr = m0 + (w * 2 + q) * 16 + lg * 4;
                #pragma unroll
                for (int i = 0; i < 4; ++i)
                    A[(mr + i) * 300 + n] = (acc[q][nt][i] + bias) * NL2E;
            }
        }
}

#define K2_STEP(P, tval, ASLOT, APTR, HPME, HPOTHER)                            \
    {                                                                           \
        const int t = (tval);                                                   \
        const int tt = t - 1;                                                   \
        const size_t so = (size_t)(tt >> 6) * 76800 + (size_t)(tt & 63) * 600;  \
        bf16x8 bfr[10];                                                         \
        _Pragma("unroll")                                                       \
        for (int kt = 0; kt < 10; ++kt)                                         \
            bfr[kt] = *(const bf16x8*)&hlds[P][(kt * 64 + l) * 8];              \
        f32x4 acc[3], accB[3];                                                  \
        _Pragma("unroll")                                                       \
        for (int q = 0; q < 3; ++q) {                                           \
            acc[q] = QOK(q) ? ASLOT[q] : (f32x4){0.f,0.f,0.f,0.f};              \
            accB[q] = (f32x4){0.f,0.f,0.f,0.f};                                 \
        }                                                                       \
        _Pragma("unroll")                                                       \
        for (int q = 0; q < 3; ++q)                                             \
            if (QOK(q)) ASLOT[q] = *(const f32x4*)(APTR + rq[q] * 4);           \
        APTR += 2400;                                                           \
        __builtin_amdgcn_s_setprio(1);                                          \
        _Pragma("unroll")                                                       \
        for (int kt = 0; kt < 5; ++kt) {                                        \
            acc[0]  = __builtin_amdgcn_mfma_f32_16x16x32_bf16(afrag[0][kt],   bfr[kt],   acc[0],  0, 0, 0); \
            accB[0] = __builtin_amdgcn_mfma_f32_16x16x32_bf16(afrag[0][kt+5], bfr[kt+5], accB[0], 0, 0, 0); \
            acc[1]  = __builtin_amdgcn_mfma_f32_16x16x32_bf16(afrag[1][kt],   bfr[kt],   acc[1],  0, 0, 0); \
            accB[1] = __builtin_amdgcn_mfma_f32_16x16x32_bf16(afrag[1][kt+5], bfr[kt+5], accB[1], 0, 0, 0); \
            if (w4) {                                                           \
                acc[2]  = __builtin_amdgcn_mfma_f32_16x16x32_bf16(afrag[2][kt],   bfr[kt],   acc[2],  0, 0, 0); \
                accB[2] = __builtin_amdgcn_mfma_f32_16x16x32_bf16(afrag[2][kt+5], bfr[kt+5], accB[2], 0, 0, 0); \
            }                                                                   \
        }                                                                       \
        __builtin_amdgcn_s_setprio(0);                                          \
        _Pragma("unroll")                                                       \
        for (int q = 0; q < 3; ++q) {                                           \
            if (!QOK(q)) continue;                                              \
            f32x4 hv;                                                           \
            _Pragma("unroll")                                                   \
            for (int i = 0; i < 4; ++i) {                                       \
                float zn = acc[q][i] + accB[q][i];                              \
                float ex, sg;                                                   \
                asm("v_exp_f32 %0, %1" : "=v"(ex) : "v"(zn));                   \
                asm("v_rcp_f32 %0, %1" : "=v"(sg) : "v"(1.0f + ex));            \
                hv[i] = sg;                                                     \
            }                                                                   \
            unsigned plo, phi;                                                  \
            asm("v_cvt_pk_bf16_f32 %0, %1, %2" : "=v"(plo) : "v"(hv[0]), "v"(hv[1])); \
            asm("v_cvt_pk_bf16_f32 %0, %1, %2" : "=v"(phi) : "v"(hv[2]), "v"(hv[3])); \
            HPME[q].x = plo; HPME[q].y = phi;                                   \
            *(uint2*)((char*)hlds + ((P) ^ 1) * 10240 + ldsoff[q]) = HPME[q];   \
            if (t > 0 && rq[q] < 300)                                           \
                *(uint2*)(sbase + so + rq[q] * 2) = HPOTHER[q];                 \
        }                                                                       \
        asm volatile("s_waitcnt lgkmcnt(0)" ::: "memory");                      \
        __builtin_amdgcn_s_barrier();                                           \
        asm volatile("" ::: "memory");                                          \
    }

__global__ __launch_bounds__(512) void elman_rec_mfma(
    const float* __restrict__ W1, float* __restrict__ buf,
    float* __restrict__ hfinal)
{
    __shared__ unsigned short hlds[2][10 * 64 * 8];
    const int tid = threadIdx.x;
    const int w = tid >> 6, l = tid & 63, lg = l >> 4, ln = l & 15;
    const bool w4 = (w < 4);
    const int bb = blockIdx.x * 16 + ln;

    int rq[3], ldsoff[3];
    #pragma unroll
    for (int q = 0; q < 3; ++q) {
        int tile = w4 ? (3 * w + q) : (12 + 2 * (w - 4) + q);
        int r = tile * 16 + 4 * lg;
        rq[q] = r;
        ldsoff[q] = (((r >> 5) * 64 + ((r >> 3) & 3) * 16 + ln) * 8 + (r & 7)) * 2;
    }

    bf16x8 afrag[3][10];
    #pragma unroll
    for (int q = 0; q < 3; ++q) {
        #pragma unroll
        for (int kt = 0; kt < 10; ++kt) {
            bool qa = (q < 2) || w4;
            int tile = w4 ? (3 * w + q) : (12 + 2 * (w - 4) + q);
            int r = tile * 16 + ln;
            int k0 = kt * 32 + lg * 8;
            uint4 p = load8_cvt_s(W1 + (size_t)r * 600 + 300 + k0,
                                  qa && r < 300, 300 - k0, NL2E);
            union { uint4 u; bf16x8 s; } cv; cv.u = p;
            afrag[q][kt] = cv.s;
        }
    }

    for (int i = tid; i < 10 * 64 * 8; i += 512) hlds[0][i] = 0;

    const char* abase = (const char*)(buf + (size_t)bb * T_ * 300);
    char* sbase = (char*)buf + (size_t)bb * 16 * 76800;

    f32x4 A0[3], A1[3];
    #pragma unroll
    for (int q = 0; q < 3; ++q)
        if (QOK(q)) {
            A0[q] = *(const f32x4*)(abase + rq[q] * 4);
            A1[q] = *(const f32x4*)(abase + 1200 + rq[q] * 4);
        }
    const char* aptr0 = abase + 2400;
    const char* aptr1 = abase + 3600;
    uint2 hpA[3], hpB[3];
    __syncthreads();

    for (int t2 = 0; t2 < T_; t2 += 2) {
        K2_STEP(0, t2,     A0, aptr0, hpA, hpB)
        K2_STEP(1, t2 + 1, A1, aptr1, hpB, hpA)
    }

    {
        const int tt = T_ - 1;
        const size_t so = (size_t)(tt >> 6) * 76800 + (size_t)(tt & 63) * 600;
        #pragma unroll
        for (int q = 0; q < 3; ++q)
            if (QOK(q) && rq[q] < 300) {
                *(uint2*)(sbase + so + rq[q] * 2) = hpB[q];
                f32x4 hv;
                union { float f; unsigned u; } c0, c1, c2, c3;
                c0.u = hpB[q].x << 16; c1.u = hpB[q].x & 0xFFFF0000u;
                c2.u = hpB[q].y << 16; c3.u = hpB[q].y & 0xFFFF0000u;
                hv[0] = c0.f; hv[1] = c1.f; hv[2] = c2.f; hv[3] = c3.f;
                *(f32x4*)(hfinal + bb * 300 + rq[q]) = hv;
            }
    }
}

__global__ __launch_bounds__(256) void gemm_out(
    float* __restrict__ buf, const float* __restrict__ W2,
    const float* __restrict__ b2)
{
    __shared__ unsigned short alds[4 * 64 * 8];
    __shared__ unsigned short blds[19 * 64 * 8];
    const int tid = threadIdx.x;
    const int w = tid >> 6, l = tid & 63, lg = l >> 4, ln = l & 15;
    const size_t chunk = blockIdx.x;
    const char* pbase = (const char*)buf + chunk * 76800;

    f32x4 acc[19];
    #pragma unroll
    for (int nt = 0; nt < 19; ++nt) acc[nt] = (f32x4){0.f,0.f,0.f,0.f};

    for (int kt = 0; kt < 10; ++kt) {
        const int kc = kt * 32;
        __syncthreads();
        {
            int row = tid >> 2, kh = tid & 3;
            int k0 = kc + kh * 8;
            const char* p = pbase + row * 600;
            uint2 lo = make_uint2(0u, 0u), hi = make_uint2(0u, 0u);
            int krem = 300 - k0;
            if (krem >= 8)      { lo = *(const uint2*)(p + k0 * 2); hi = *(const uint2*)(p + k0 * 2 + 8); }
            else if (krem >= 4) { lo = *(const uint2*)(p + k0 * 2); }
            uint4 pk; pk.x = lo.x; pk.y = lo.y; pk.z = hi.x; pk.w = hi.y;
            *(uint4*)&alds[(((row >> 4) * 64) + kh * 16 + (row & 15)) * 8] = pk;
        }
        #pragma unroll
        for (int rep = 0; rep < 5; ++rep) {
            int e = tid + rep * 256;
            if (e < 1216) {
                int nn = e >> 2, kh = e & 3;
                int k0 = kc + kh * 8;
                uint4 p = load8_cvt(W2 + (size_t)nn * 300 + k0, nn < 300, 300 - k0);
                *(uint4*)&blds[(((nn >> 4) * 64) + kh * 16 + (nn & 15)) * 8] = p;
            }
        }
        __syncthreads();
        bf16x8 afr = *(const bf16x8*)&alds[(w * 64 + l) * 8];
        #pragma unroll
        for (int nt = 0; nt < 19; ++nt) {
            bf16x8 bfr = *(const bf16x8*)&blds[(nt * 64 + l) * 8];
            acc[nt] = __builtin_amdgcn_mfma_f32_16x16x32_bf16(afr, bfr, acc[nt], 0, 0, 0);
        }
    }

    float* frow = buf + chunk * 19200;
    #pragma unroll
    for (int nt = 0; nt < 19; ++nt) {
        int n = nt * 16 + ln;
        if (n < 300) {
            float bias = b2[n];
            int mr = w * 16 + lg * 4;
            #pragma unroll
            for (int i = 0; i < 4; ++i)
                frow[(mr + i) * 300 + n] = acc[nt][i] + bias;
        }
    }
}

// ---------------------------------------------------------------------------
extern "C" void kernel_launch(void* const* d_in, const int* in_sizes, int n_in,
                              void* d_out, int out_size, void* d_ws, size_t ws_size,
                              hipStream_t stream)
{
    const float* x  = (const float*)d_in[0];
    const float* W1 = (const float*)d_in[1];
    const float* b1 = (const float*)d_in[2];
    const float* W2 = (const float*)d_in[3];
    const float* b2 = (const float*)d_in[4];

    float* out    = (float*)d_out;
    float* hfinal = out + (size_t)HB;

    if (ws_size >= WOFF + 2 * WSZ1) {
        // full path: pre-converted W + time-major h in ws
        char* ws  = (char*)d_ws;
        char* wbf = ws + WOFF;
        convert_w<<<20, 256, 0, stream>>>(W1, W2, wbf);
        gemm_in_t2b<<<512, 512, 0, stream>>>(x, wbf, b1, ws);
        elman_rec_ws<<<8, 512, 0, stream>>>(W1, hfinal, ws);
        gemm_out_t2b<<<512, 512, 0, stream>>>(ws, wbf + WSZ1, b2, out);
    } else if (ws_size >= HT4 + 2 * 76800) {
        // middle path: time-major h in ws, inline W conversion
        gemm_in_t2<<<512, 512, 0, stream>>>(x, W1, b1, (char*)d_ws);
        elman_rec_ws<<<8, 512, 0, stream>>>(W1, hfinal, (char*)d_ws);
        gemm_out_t2<<<512, 512, 0, stream>>>((const char*)d_ws, W2, b2, out);
    } else {
        // fallback: everything in d_out
        gemm_in<<<dim3(1024, 2), 256, 0, stream>>>(x, W1, b1, out);
        elman_rec_mfma<<<8, 512, 0, stream>>>(W1, out, hfinal);
        gemm_out<<<2048, 256, 0, stream>>>(out, W2, b2);
    }
}